// Round 9
// baseline (897.336 us; speedup 1.0000x reference)
//
#include <hip/hip_runtime.h>
#include <math.h>

typedef __bf16 bf16_t;
typedef __bf16 bf16x4 __attribute__((ext_vector_type(4)));
typedef __bf16 bf16x8 __attribute__((ext_vector_type(8)));
typedef _Float16 f16x4 __attribute__((ext_vector_type(4)));
typedef _Float16 f16x8 __attribute__((ext_vector_type(8)));
typedef float f32x4 __attribute__((ext_vector_type(4)));
typedef int i32x4 __attribute__((ext_vector_type(4)));

#define MFMA_BF16 __builtin_amdgcn_mfma_f32_16x16x32_bf16
#define MFMA_F16  __builtin_amdgcn_mfma_f32_16x16x32_f16
#define SB0 __builtin_amdgcn_sched_barrier(0)

// ---------- helpers ----------

__device__ __forceinline__ bf16_t to_bf16_rne(float x, float& rep) {
    unsigned u = __builtin_bit_cast(unsigned, x);
    unsigned r = u + 0x7fffu + ((u >> 16) & 1u);
    unsigned short h = (unsigned short)(r >> 16);
    rep = __builtin_bit_cast(float, ((unsigned)h) << 16);
    return __builtin_bit_cast(bf16_t, h);
}

__device__ __forceinline__ void g2l16(const void* g, void* l) {
    __builtin_amdgcn_global_load_lds(
        (const __attribute__((address_space(1))) unsigned int*)g,
        (__attribute__((address_space(3))) unsigned int*)l, 16, 0, 0);
}

// swizzled element offset of 16B-chunk (row r in 0..255, chunk j in 0..7);
// rows are 128B. j ^= (r&7): involution, applied on pre-swizzled global
// source AND on every ds_read. 16-row read spans -> 2-way (free) bank aliasing.
__device__ __forceinline__ int lch(int r, int j) {
    return (r * 8 + (j ^ (r & 7))) * 8;
}

// stage one K-tile with 1024 threads: A 256 rows x 128B + B 256 rows x 128B.
// 4 loads/thread (2 A + 2 B). Linear LDS dest, pre-swizzled global source.
template <typename T>
__device__ __forceinline__ void stage2(const T* __restrict__ gA, long long ldA,
                                       const T* __restrict__ gB, long long ldB,
                                       T* buf, int tid) {
    int wid = tid >> 6, lane = tid & 63;
#pragma unroll
    for (int i = 0; i < 2; ++i) {
        int cb = i * 1024 + wid * 64;
        int c = cb + lane;
        int r = c >> 3, j = (c & 7) ^ (r & 7);
        g2l16(gA + (long long)r * ldA + j * 8, buf + (size_t)cb * 8);
    }
#pragma unroll
    for (int i = 0; i < 2; ++i) {
        int cb = i * 1024 + wid * 64;
        int c = cb + lane;
        int r = c >> 3, j = (c & 7) ^ (r & 7);
        g2l16(gB + (long long)r * ldB + j * 8, buf + 16384 + (size_t)cb * 8);
    }
}

// ---------- elementwise prep kernels ----------

// f32 [rows][1024] -> interleaved bf16 hi/lo: row stride 2048, 32-k blocks [32 hi|32 lo]
__global__ __launch_bounds__(256) void split_int_k(const float* __restrict__ in,
                                                   bf16_t* __restrict__ out,
                                                   long long n4) {
    long long i = (long long)blockIdx.x * 256 + threadIdx.x;
    if (i >= n4) return;
    f32x4 v = ((const f32x4*)in)[i];
    bf16x4 hv, lv;
#pragma unroll
    for (int j = 0; j < 4; ++j) {
        float rep;
        hv[j] = to_bf16_rne(v[j], rep);
        float res = v[j] - rep;
        float rep2;
        lv[j] = to_bf16_rne(res, rep2);
    }
    long long row = i >> 8;
    int k = (int)(i & 255) * 4;
    long long base = row * 2048 + ((k >> 5) << 6) + (k & 31);
    *(bf16x4*)(out + base) = hv;
    *(bf16x4*)(out + base + 32) = lv;
}

__global__ __launch_bounds__(256) void cast_f16_k(const float* __restrict__ in,
                                                  _Float16* __restrict__ o, long long n4) {
    long long i = (long long)blockIdx.x * 256 + threadIdx.x;
    if (i >= n4) return;
    f32x4 v = ((const f32x4*)in)[i];
    f16x4 h;
#pragma unroll
    for (int j = 0; j < 4; ++j) h[j] = (_Float16)v[j];
    ((f16x4*)o)[i] = h;
}

// fused: ctx chunk [G][1024][1024] f32 -> ctx_int (interleaved hi/lo bf16, rows 2048)
//        AND ctxT [G][1024(d)][1024(k)] f16   (reads ctx ONCE)
__global__ __launch_bounds__(256) void prep_ctx_k(const float* __restrict__ ctx,
                                                  bf16_t* __restrict__ ctx_int,
                                                  _Float16* __restrict__ ctxT) {
    __shared__ _Float16 tl[32][33];
    int b = blockIdx.z;
    int k0 = blockIdx.x * 32, d0 = blockIdx.y * 32;
    const float* src = ctx + ((long long)b * 1024 + k0) * 1024 + d0;
    int x = threadIdx.x, y = threadIdx.y;  // 32 x 8
#pragma unroll
    for (int i = 0; i < 4; ++i) {
        int k = y + i * 8;
        float v = src[(long long)k * 1024 + x];
        float rep;
        bf16_t hb = to_bf16_rne(v, rep);
        float rep2;
        bf16_t lb = to_bf16_rne(v - rep, rep2);
        long long rb = ((long long)b * 1024 + k0 + k) * 2048 + d0 * 2 + x;
        ctx_int[rb] = hb;
        ctx_int[rb + 32] = lb;
        tl[x][k] = (_Float16)v;
    }
    __syncthreads();
    _Float16* dst = ctxT + ((long long)b * 1024 + d0) * 1024 + k0;
#pragma unroll
    for (int i = 0; i < 4; ++i) {
        int dd = y + i * 8;
        dst[(long long)dd * 1024 + x] = tl[dd][x];
    }
}

// per-row masked softmax: w_k = m_k*exp(s_k - max)/sum  (fp32 in, f16 out)
__global__ __launch_bounds__(256) void masked_softmax_k(const float* __restrict__ s,
                                                        const int* __restrict__ m,
                                                        _Float16* __restrict__ w) {
    long long row = blockIdx.x;
    const f32x4* sr = (const f32x4*)(s + row * 1024);
    const i32x4* mr = (const i32x4*)(m + row * 1024);
    f16x4* wr_ = (f16x4*)(w + row * 1024);
    int t = threadIdx.x;
    int lane = t & 63, wid = t >> 6;
    f32x4 v = sr[t];
    i32x4 mk = mr[t];
    float mx = -3.0e38f;
#pragma unroll
    for (int i = 0; i < 4; ++i)
        if (mk[i]) mx = fmaxf(mx, v[i]);
#pragma unroll
    for (int off = 32; off; off >>= 1) mx = fmaxf(mx, __shfl_xor(mx, off));
    __shared__ float rm[4], rs[4];
    if (!lane) rm[wid] = mx;
    __syncthreads();
    mx = fmaxf(fmaxf(rm[0], rm[1]), fmaxf(rm[2], rm[3]));
    float sum = 0.f;
    f32x4 e;
#pragma unroll
    for (int i = 0; i < 4; ++i) {
        e[i] = mk[i] ? expf(v[i] - mx) : 0.f;
        sum += e[i];
    }
#pragma unroll
    for (int off = 32; off; off >>= 1) sum += __shfl_xor(sum, off);
    if (!lane) rs[wid] = sum;
    __syncthreads();
    sum = rs[0] + rs[1] + rs[2] + rs[3];
    float inv = sum > 0.f ? 1.0f / sum : 0.f;
    f16x4 o;
#pragma unroll
    for (int i = 0; i < 4; ++i) o[i] = (_Float16)(e[i] * inv);
    wr_[t] = o;
}

// ---------- 256x256 dbuf bf16x3 GEMM, 16 waves (4x4), wave tile 64x64 ----------
// A,B: interleaved hi/lo pair layout, rows of 2048 elements, K=1024 (BK=32).
// acc[4][4] = 64 VGPR -> <=128 regs/wave -> 4 waves/SIMD (16 waves/CU).
// Per tile: vmcnt(4) ; barrier ; read B+A01 ; MFMA m0,m1 ; read A23 ;
// lgkm(0) ; barrier ; stage(t+2) ; MFMA m2,m3.
// EPI 0: f32 scores (ld 1024, +z*sC). EPI 1: qint interleaved + qf f16.
template <int EPI>
__global__ __launch_bounds__(1024, 4) void gemm_x3_256(
    const bf16_t* __restrict__ Aint, const bf16_t* __restrict__ Bint,
    long long sA, long long sB, long long sC, int nbx, int nby,
    float* __restrict__ Cs, bf16_t* __restrict__ Qint, _Float16* __restrict__ Qf) {
    __shared__ bf16_t lds[65536];
    const int NT = 32;
    int tid = threadIdx.x, lane = tid & 63, wid = tid >> 6;
    int wr = wid >> 2, wc = wid & 3;
    int nwg = gridDim.x;
    int bid = blockIdx.x;
    int lid = (bid & 7) * (nwg >> 3) + (bid >> 3);   // XCD-contiguous remap
    int by = lid % nby;
    int t2_ = lid / nby;
    int bx = t2_ % nbx;
    int z = t2_ / nbx;
    const bf16_t* At = Aint + (long long)z * sA + (long long)bx * 256 * 2048;
    const bf16_t* Bt = Bint + (long long)z * sB + (long long)by * 256 * 2048;
    stage2(At, 2048ll, Bt, 2048ll, lds, tid);
    stage2(At + 64, 2048ll, Bt + 64, 2048ll, lds + 32768, tid);
    f32x4 acc[4][4] = {};
    int l15 = lane & 15, l4 = lane >> 4;
    for (int t = 0; t < NT; ++t) {
        bf16_t* buf = lds + (size_t)(t & 1) * 32768;
        bf16_t* bufB = buf + 16384;
        bool st = (t + 2 < NT);
        if (t < NT - 1) {
            asm volatile("s_waitcnt vmcnt(4)" ::: "memory");
        } else {
            asm volatile("s_waitcnt vmcnt(0)" ::: "memory");
        }
        SB0;
        __builtin_amdgcn_s_barrier();
        SB0;
        // reads: B all (8 b128) + A m0,m1 (4 b128)
        bf16x8 bh[4], bl[4];
#pragma unroll
        for (int n = 0; n < 4; ++n) {
            int rB = wc * 64 + n * 16 + l15;
            bh[n] = *(const bf16x8*)(bufB + lch(rB, l4));
            bl[n] = *(const bf16x8*)(bufB + lch(rB, 4 + l4));
        }
        bf16x8 ah0[2], al0[2];
#pragma unroll
        for (int i = 0; i < 2; ++i) {
            int rA = wr * 64 + i * 16 + l15;
            ah0[i] = *(const bf16x8*)(buf + lch(rA, l4));
            al0[i] = *(const bf16x8*)(buf + lch(rA, 4 + l4));
        }
        __builtin_amdgcn_s_setprio(1);
#pragma unroll
        for (int i = 0; i < 2; ++i)
#pragma unroll
            for (int n = 0; n < 4; ++n) {
                f32x4 a = acc[i][n];
                a = MFMA_BF16(ah0[i], bh[n], a, 0, 0, 0);
                a = MFMA_BF16(ah0[i], bl[n], a, 0, 0, 0);
                a = MFMA_BF16(al0[i], bh[n], a, 0, 0, 0);
                acc[i][n] = a;
            }
        __builtin_amdgcn_s_setprio(0);
        // read A m2,m3
        bf16x8 ah1[2], al1[2];
#pragma unroll
        for (int i = 0; i < 2; ++i) {
            int rA = wr * 64 + (2 + i) * 16 + l15;
            ah1[i] = *(const bf16x8*)(buf + lch(rA, l4));
            al1[i] = *(const bf16x8*)(buf + lch(rA, 4 + l4));
        }
        asm volatile("s_waitcnt lgkmcnt(0)" ::: "memory");
        SB0;
        __builtin_amdgcn_s_barrier();   // all waves done reading buf
        SB0;
        if (st)
            stage2(At + (long long)(t + 2) * 64, 2048ll,
                   Bt + (long long)(t + 2) * 64, 2048ll, buf, tid);
        __builtin_amdgcn_s_setprio(1);
#pragma unroll
        for (int i = 0; i < 2; ++i)
#pragma unroll
            for (int n = 0; n < 4; ++n) {
                f32x4 a = acc[2 + i][n];
                a = MFMA_BF16(ah1[i], bh[n], a, 0, 0, 0);
                a = MFMA_BF16(ah1[i], bl[n], a, 0, 0, 0);
                a = MFMA_BF16(al1[i], bh[n], a, 0, 0, 0);
                acc[2 + i][n] = a;
            }
        __builtin_amdgcn_s_setprio(0);
        SB0;
    }
    int r0 = bx * 256 + wr * 64 + (l4 << 2);
    int c0 = by * 256 + wc * 64 + l15;
#pragma unroll
    for (int m = 0; m < 4; ++m)
#pragma unroll
        for (int n = 0; n < 4; ++n)
#pragma unroll
            for (int j = 0; j < 4; ++j) {
                int r = r0 + m * 16 + j;
                int c = c0 + n * 16;
                float v = acc[m][n][j];
                if (EPI == 0) {
                    Cs[(long long)z * sC + (long long)r * 1024 + c] = v;
                } else {
                    float rep;
                    bf16_t hb = to_bf16_rne(v, rep);
                    float res = v - rep;
                    float rep2;
                    bf16_t lb = to_bf16_rne(res, rep2);
                    long long rb = (long long)r * 2048 + ((c >> 5) << 6) + (c & 31);
                    Qint[rb] = hb;
                    Qint[rb + 32] = lb;
                    Qf[(long long)r * 1024 + c] = (_Float16)v;
                }
            }
}

// ---------- 256x256 dbuf f16 GEMM, 16 waves (4x4), wave tile 64x64 (BK=64) ----------
// A rows K-contig (ldA), optional A-source switch at tile swt. B rows K-contig.
// EPI 0: f16 out (ld 1024, +z*sC). EPI 1: f32 tanh out (ld 1024).
template <int EPI>
__global__ __launch_bounds__(1024, 4) void gemm_f16_256(
    const _Float16* __restrict__ A1, const _Float16* __restrict__ A2,
    const _Float16* __restrict__ B,
    long long ldA, long long ldB, long long sA, long long sB, long long sC,
    int NT, int swt, int nbx, int nby,
    _Float16* __restrict__ Cm, float* __restrict__ Co) {
    __shared__ _Float16 lds[65536];
    int tid = threadIdx.x, lane = tid & 63, wid = tid >> 6;
    int wr = wid >> 2, wc = wid & 3;
    int nwg = gridDim.x;
    int bid = blockIdx.x;
    int lid = (bid & 7) * (nwg >> 3) + (bid >> 3);
    int by = lid % nby;
    int t2_ = lid / nby;
    int bx = t2_ % nbx;
    int z = t2_ / nbx;
    const _Float16* A1t = A1 + (long long)z * sA + (long long)bx * 256 * ldA;
    const _Float16* A2t = A2 + (long long)bx * 256 * ldA;
    const _Float16* Bt = B + (long long)z * sB + (long long)by * 256 * ldB;
    stage2((0 < swt) ? A1t : A2t, ldA, Bt, ldB, lds, tid);
    stage2((1 < swt) ? A1t + 64 : A2t + (long long)(1 - swt) * 64, ldA, Bt + 64, ldB,
           lds + 32768, tid);
    f32x4 acc[4][4] = {};
    int l15 = lane & 15, l4 = lane >> 4;
    for (int t = 0; t < NT; ++t) {
        _Float16* buf = lds + (size_t)(t & 1) * 32768;
        _Float16* bufB = buf + 16384;
        int tt = t + 2;
        bool st = (tt < NT);
        const _Float16* gA2 =
            (tt < swt) ? A1t + (long long)tt * 64 : A2t + (long long)(tt - swt) * 64;
        const _Float16* gB2 = Bt + (long long)tt * 64;
        if (t < NT - 1) {
            asm volatile("s_waitcnt vmcnt(4)" ::: "memory");
        } else {
            asm volatile("s_waitcnt vmcnt(0)" ::: "memory");
        }
        SB0;
        __builtin_amdgcn_s_barrier();
        SB0;
        f16x8 bfr[4][2];
#pragma unroll
        for (int n = 0; n < 4; ++n) {
            int rB = wc * 64 + n * 16 + l15;
#pragma unroll
            for (int ks = 0; ks < 2; ++ks)
                bfr[n][ks] = *(const f16x8*)(bufB + lch(rB, ks * 4 + l4));
        }
        f16x8 a0[2][2];
#pragma unroll
        for (int i = 0; i < 2; ++i)
#pragma unroll
            for (int ks = 0; ks < 2; ++ks) {
                int rA = wr * 64 + i * 16 + l15;
                a0[i][ks] = *(const f16x8*)(buf + lch(rA, ks * 4 + l4));
            }
        __builtin_amdgcn_s_setprio(1);
#pragma unroll
        for (int i = 0; i < 2; ++i)
#pragma unroll
            for (int n = 0; n < 4; ++n) {
                f32x4 v = acc[i][n];
                v = MFMA_F16(a0[i][0], bfr[n][0], v, 0, 0, 0);
                v = MFMA_F16(a0[i][1], bfr[n][1], v, 0, 0, 0);
                acc[i][n] = v;
            }
        __builtin_amdgcn_s_setprio(0);
        f16x8 a1[2][2];
#pragma unroll
        for (int i = 0; i < 2; ++i)
#pragma unroll
            for (int ks = 0; ks < 2; ++ks) {
                int rA = wr * 64 + (2 + i) * 16 + l15;
                a1[i][ks] = *(const f16x8*)(buf + lch(rA, ks * 4 + l4));
            }
        asm volatile("s_waitcnt lgkmcnt(0)" ::: "memory");
        SB0;
        __builtin_amdgcn_s_barrier();
        SB0;
        if (st) stage2(gA2, ldA, gB2, ldB, buf, tid);
        __builtin_amdgcn_s_setprio(1);
#pragma unroll
        for (int i = 0; i < 2; ++i)
#pragma unroll
            for (int n = 0; n < 4; ++n) {
                f32x4 v = acc[2 + i][n];
                v = MFMA_F16(a1[i][0], bfr[n][0], v, 0, 0, 0);
                v = MFMA_F16(a1[i][1], bfr[n][1], v, 0, 0, 0);
                acc[2 + i][n] = v;
            }
        __builtin_amdgcn_s_setprio(0);
        SB0;
    }
    int r0 = bx * 256 + wr * 64 + (l4 << 2);
    int c0 = by * 256 + wc * 64 + l15;
#pragma unroll
    for (int m = 0; m < 4; ++m)
#pragma unroll
        for (int n = 0; n < 4; ++n)
#pragma unroll
            for (int j = 0; j < 4; ++j) {
                int r = r0 + m * 16 + j;
                int c = c0 + n * 16;
                float v = acc[m][n][j];
                if (EPI == 0) {
                    Cm[(long long)z * sC + (long long)r * 1024 + c] = (_Float16)v;
                } else {
                    Co[(long long)r * 1024 + c] = tanhf(v);
                }
            }
}

// ---------- launch ----------

extern "C" void kernel_launch(void* const* d_in, const int* in_sizes, int n_in,
                              void* d_out, int out_size, void* d_ws, size_t ws_size,
                              hipStream_t stream) {
    const float* query = (const float*)d_in[0];
    const float* ctx = (const float*)d_in[1];
    const int* mask = (const int*)d_in[2];
    const float* Win = (const float*)d_in[3];
    const float* Wout = (const float*)d_in[4];
    float* outp = (float*)d_out;

    const long long MB = 1048576ll;
    // footprint: exactly 16G MiB (weights overlaid into dead slab regions).
    int G = 1;
    if ((long long)ws_size >= 512 * MB) G = 32;
    else if ((long long)ws_size >= 256 * MB) G = 16;
    else if ((long long)ws_size >= 128 * MB) G = 8;
    else if ((long long)ws_size >= 64 * MB) G = 4;
    else if ((long long)ws_size >= 32 * MB) G = 2;

    char* p = (char*)d_ws;
    const long long R = (long long)G * 1024;   // rows per chunk
    bf16_t* qint = (bf16_t*)p; p += 4 * G * MB;    // [R][2048] interleaved
    _Float16* qf = (_Float16*)p; p += 2 * G * MB;  // [R][1024]
    // slabA (4G MiB): win_int (4 MiB, GEMM1) -> ctx_int [R][2048] (GEMM2)
    //                 -> wf [R][1024] (lower 2G) + mixf [R][1024] (upper 2G)
    char* slabA = p; p += 4 * G * MB;
    bf16_t* win_int = (bf16_t*)slabA;
    bf16_t* ctx_int = (bf16_t*)slabA;
    _Float16* wf = (_Float16*)slabA;
    _Float16* mixf = (_Float16*)(slabA + 2 * G * MB);
    _Float16* ctxT = (_Float16*)p; p += 2 * G * MB;
    // slabC (4G MiB): qs_int (GEMM1 A) -> scores f32 (GEMM2/softmax) -> woutf (GEMM4 B)
    char* slabC = p;
    bf16_t* qs_int = (bf16_t*)slabC;
    float* scores = (float*)slabC;
    _Float16* woutf = (_Float16*)slabC;

    const long long LD = 1048576ll;  // 1024*1024 elements

    for (int b0 = 0; b0 < 32; b0 += G) {
        const float* qsrc = query + (long long)b0 * LD;
        const float* csrc = ctx + (long long)b0 * LD;
        // weights + query prep (win_int lives in slabA until prep_ctx overwrites it)
        split_int_k<<<1024, 256, 0, stream>>>(Win, win_int, 262144ll);
        split_int_k<<<(int)R, 256, 0, stream>>>(qsrc, qs_int, R * 256);
        // GEMM1: q = query @ Win^T (bf16x3) -> qint (interleaved) + qf (f16)
        gemm_x3_256<1><<<16 * G, 1024, 0, stream>>>(
            qs_int, win_int, 0, 0, 0, 4 * G, 4, nullptr, qint, qf);
        // fused ctx prep: ctx_int (over win_int, dead) + ctxT, reads ctx once
        prep_ctx_k<<<dim3(32, 32, G), dim3(32, 8, 1), 0, stream>>>(csrc, ctx_int, ctxT);
        // GEMM2: scores = q @ ctx^T (bf16x3) -> scores (over qs_int, dead)
        gemm_x3_256<0><<<16 * G, 1024, 0, stream>>>(
            qint, ctx_int, 2097152ll, 2097152ll, 1048576ll, 4, 4,
            scores, nullptr, nullptr);
        // softmax -> wf (over ctx_int lower half, dead)
        masked_softmax_k<<<(int)R, 256, 0, stream>>>(
            scores, mask + (long long)b0 * 1024 * 1024, wf);
        // Wout cast -> woutf (over scores, dead)
        cast_f16_k<<<2048, 256, 0, stream>>>(Wout, woutf, 524288ll);
        // GEMM3: mix = w @ ctxT^T (f16) -> mixf (over ctx_int upper half, dead)
        gemm_f16_256<0><<<16 * G, 1024, 0, stream>>>(
            wf, wf, ctxT, 1024ll, 1024ll, 1048576ll, 1048576ll, 1048576ll,
            16, 1 << 20, 4, 4, mixf, nullptr);
        // GEMM4: out = tanh(mix @ W1^T + q @ W2^T), K=2048, A-switch at tile 16
        gemm_f16_256<1><<<16 * G, 1024, 0, stream>>>(
            mixf, qf, woutf, 1024ll, 2048ll, 0, 0, 0,
            32, 16, 4 * G, 4, nullptr, outp + (long long)b0 * LD);
    }
}

// Round 10
// 781.323 us; speedup vs baseline: 1.1485x; 1.1485x over previous
//
#include <hip/hip_runtime.h>
#include <math.h>

typedef __bf16 bf16_t;
typedef __bf16 bf16x4 __attribute__((ext_vector_type(4)));
typedef __bf16 bf16x8 __attribute__((ext_vector_type(8)));
typedef _Float16 f16x4 __attribute__((ext_vector_type(4)));
typedef _Float16 f16x8 __attribute__((ext_vector_type(8)));
typedef float f32x4 __attribute__((ext_vector_type(4)));
typedef int i32x4 __attribute__((ext_vector_type(4)));

#define MFMA_BF16 __builtin_amdgcn_mfma_f32_16x16x32_bf16
#define MFMA_F16  __builtin_amdgcn_mfma_f32_16x16x32_f16
#define SB0 __builtin_amdgcn_sched_barrier(0)

#define P_PRE                                         \
    __builtin_amdgcn_sched_barrier(0);                \
    __builtin_amdgcn_s_barrier();                     \
    asm volatile("s_waitcnt lgkmcnt(0)" ::: "memory");\
    __builtin_amdgcn_sched_barrier(0);                \
    __builtin_amdgcn_s_setprio(1)
#define P_POST                                        \
    __builtin_amdgcn_s_setprio(0);                    \
    __builtin_amdgcn_sched_barrier(0);                \
    __builtin_amdgcn_s_barrier()

// ---------- helpers ----------

__device__ __forceinline__ bf16_t to_bf16_rne(float x, float& rep) {
    unsigned u = __builtin_bit_cast(unsigned, x);
    unsigned r = u + 0x7fffu + ((u >> 16) & 1u);
    unsigned short h = (unsigned short)(r >> 16);
    rep = __builtin_bit_cast(float, ((unsigned)h) << 16);
    return __builtin_bit_cast(bf16_t, h);
}

__device__ __forceinline__ void g2l16(const void* g, void* l) {
    __builtin_amdgcn_global_load_lds(
        (const __attribute__((address_space(1))) unsigned int*)g,
        (__attribute__((address_space(3))) unsigned int*)l, 16, 0, 0);
}

// swizzled element offset of 16B-chunk (row r in 0..255, chunk j in 0..7);
// rows are 128B. j ^= (r&7): involution, applied on the staging side
// (pre-swizzled glds source / swizzled ds_write) AND on every ds_read.
__device__ __forceinline__ int lch(int r, int j) {
    return (r * 8 + (j ^ (r & 7))) * 8;
}

// glds-stage one 256-row x 128B interleaved tile (ld 2048) into dst. 4 loads/thread.
__device__ __forceinline__ void stageG(const bf16_t* __restrict__ g, bf16_t* dst,
                                       int tid) {
    int wid = tid >> 6, lane = tid & 63;
#pragma unroll
    for (int i = 0; i < 4; ++i) {
        int cb = i * 512 + wid * 64;
        int c = cb + lane;
        int r = c >> 3, j = (c & 7) ^ (r & 7);
        g2l16(g + (long long)r * 2048 + j * 8, dst + (size_t)cb * 8);
    }
}

// f32 operand staging: thread (r = tid>>1, half h = tid&1) loads 16 consecutive
// f32 of row r (k offset h*16 within the 32-k tile). ld = 1024 f32.
__device__ __forceinline__ void ldf32(const float* __restrict__ g, int tid,
                                      f32x4* v) {
    int r = tid >> 1, h = tid & 1;
    const f32x4* s = (const f32x4*)(g + (long long)r * 1024 + h * 16);
#pragma unroll
    for (int i = 0; i < 4; ++i) v[i] = s[i];
}

// convert 16 f32 -> bf16 hi/lo, write to swizzled interleaved LDS tile row r:
// [32 hi | 32 lo]; hi chunks h*2,h*2+1; lo chunks 4+h*2,4+h*2+1.
__device__ __forceinline__ void wrsplit(bf16_t* dst, int tid, const f32x4* v) {
    int r = tid >> 1, h = tid & 1;
    bf16x8 H[2], L[2];
#pragma unroll
    for (int e = 0; e < 16; ++e) {
        float x = v[e >> 2][e & 3];
        float rep;
        bf16_t hb = to_bf16_rne(x, rep);
        float r2;
        bf16_t lb = to_bf16_rne(x - rep, r2);
        H[e >> 3][e & 7] = hb;
        L[e >> 3][e & 7] = lb;
    }
    *(bf16x8*)(dst + lch(r, h * 2)) = H[0];
    *(bf16x8*)(dst + lch(r, h * 2 + 1)) = H[1];
    *(bf16x8*)(dst + lch(r, 4 + h * 2)) = L[0];
    *(bf16x8*)(dst + lch(r, 4 + h * 2 + 1)) = L[1];
}

__device__ __forceinline__ void stageA4h(const _Float16* __restrict__ gA, long long ldA,
                                         _Float16* buf, int tid) {
    int wid = tid >> 6, lane = tid & 63;
#pragma unroll
    for (int i = 0; i < 4; ++i) {
        int cb = i * 512 + wid * 64;
        int c = cb + lane;
        int r = c >> 3, j = (c & 7) ^ (r & 7);
        g2l16(gA + (long long)r * ldA + j * 8, buf + (size_t)cb * 8);
    }
}
__device__ __forceinline__ void stageB4h(const _Float16* __restrict__ gB, long long ldB,
                                         _Float16* buf, int tid) {
    int wid = tid >> 6, lane = tid & 63;
#pragma unroll
    for (int i = 0; i < 4; ++i) {
        int cb = i * 512 + wid * 64;
        int c = cb + lane;
        int r = c >> 3, j = (c & 7) ^ (r & 7);
        g2l16(gB + (long long)r * ldB + j * 8, buf + 16384 + (size_t)cb * 8);
    }
}
__device__ __forceinline__ void stage2h(const _Float16* __restrict__ gA, long long ldA,
                                        const _Float16* __restrict__ gB, long long ldB,
                                        _Float16* buf, int tid) {
    stageA4h(gA, ldA, buf, tid);
    stageB4h(gB, ldB, buf, tid);
}

// ---------- elementwise prep kernels ----------

__global__ __launch_bounds__(256) void split_int_k(const float* __restrict__ in,
                                                   bf16_t* __restrict__ out,
                                                   long long n4) {
    long long i = (long long)blockIdx.x * 256 + threadIdx.x;
    if (i >= n4) return;
    f32x4 v = ((const f32x4*)in)[i];
    bf16x4 hv, lv;
#pragma unroll
    for (int j = 0; j < 4; ++j) {
        float rep;
        hv[j] = to_bf16_rne(v[j], rep);
        float res = v[j] - rep;
        float rep2;
        lv[j] = to_bf16_rne(res, rep2);
    }
    long long row = i >> 8;
    int k = (int)(i & 255) * 4;
    long long base = row * 2048 + ((k >> 5) << 6) + (k & 31);
    *(bf16x4*)(out + base) = hv;
    *(bf16x4*)(out + base + 32) = lv;
}

__global__ __launch_bounds__(256) void cast_f16_k(const float* __restrict__ in,
                                                  _Float16* __restrict__ o, long long n4) {
    long long i = (long long)blockIdx.x * 256 + threadIdx.x;
    if (i >= n4) return;
    f32x4 v = ((const f32x4*)in)[i];
    f16x4 h;
#pragma unroll
    for (int j = 0; j < 4; ++j) h[j] = (_Float16)v[j];
    ((f16x4*)o)[i] = h;
}

// ctx chunk [G][1024][1024] f32 -> ctxT [G][1024(d)][1024(k)] f16
__global__ __launch_bounds__(256) void transpose_ctx_k(const float* __restrict__ ctx,
                                                       _Float16* __restrict__ ctxT) {
    __shared__ _Float16 tl[32][33];
    int b = blockIdx.z;
    int k0 = blockIdx.x * 32, d0 = blockIdx.y * 32;
    const float* src = ctx + ((long long)b * 1024 + k0) * 1024 + d0;
    int x = threadIdx.x, y = threadIdx.y;  // 32 x 8
#pragma unroll
    for (int i = 0; i < 4; ++i) {
        int k = y + i * 8;
        tl[x][k] = (_Float16)src[(long long)k * 1024 + x];
    }
    __syncthreads();
    _Float16* dst = ctxT + ((long long)b * 1024 + d0) * 1024 + k0;
#pragma unroll
    for (int i = 0; i < 4; ++i) {
        int dd = y + i * 8;
        dst[(long long)dd * 1024 + x] = tl[dd][x];
    }
}

// softmax over sentinel-masked scores (-3e38 = masked).
// w_k = exp(s_k - max)/sum ; all-masked row -> zeros.
__global__ __launch_bounds__(256) void masked_softmax_k(const float* __restrict__ s,
                                                        _Float16* __restrict__ w) {
    long long row = blockIdx.x;
    const f32x4* sr = (const f32x4*)(s + row * 1024);
    f16x4* wr_ = (f16x4*)(w + row * 1024);
    int t = threadIdx.x;
    int lane = t & 63, wid = t >> 6;
    f32x4 v = sr[t];
    float mx = fmaxf(fmaxf(v[0], v[1]), fmaxf(v[2], v[3]));
#pragma unroll
    for (int off = 32; off; off >>= 1) mx = fmaxf(mx, __shfl_xor(mx, off));
    __shared__ float rm[4], rs[4];
    if (!lane) rm[wid] = mx;
    __syncthreads();
    mx = fmaxf(fmaxf(rm[0], rm[1]), fmaxf(rm[2], rm[3]));
    float sum = 0.f;
    f32x4 e;
#pragma unroll
    for (int i = 0; i < 4; ++i) {
        e[i] = expf(v[i] - mx);   // masked entry: -3e38 - mx -> 0
        sum += e[i];
    }
#pragma unroll
    for (int off = 32; off; off >>= 1) sum += __shfl_xor(sum, off);
    if (!lane) rs[wid] = sum;
    __syncthreads();
    sum = rs[0] + rs[1] + rs[2] + rs[3];
    float inv = (mx < -1.0e38f) ? 0.f : 1.0f / sum;
    f16x4 o;
#pragma unroll
    for (int i = 0; i < 4; ++i) o[i] = (_Float16)(e[i] * inv);
    wr_[t] = o;
}

// ---------- 256x256 dbuf bf16x3 GEMM, 4-phase, fused f32-operand staging ----------
// glds operand = pre-split interleaved bf16; f32 operand = raw fp32, reg-staged
// (load P0 -> convert + swizzled ds_write P3). F32A: f32 operand is A (GEMM1)
// else B (GEMM2). Overwrite invariants (lgkm0+barrier pairs) = round-7 build.
// EPI 0: sentinel-masked f32 scores (reads Mk). EPI 1: qint interleaved + qf f16.
template <int EPI, bool F32A>
__global__ __launch_bounds__(512, 2) void gemm_x3_256(
    const bf16_t* __restrict__ Gint, const float* __restrict__ Fsrc,
    const int* __restrict__ Mk,
    long long sG, long long sF, long long sC, int nbx, int nby,
    float* __restrict__ Cs, bf16_t* __restrict__ Qint, _Float16* __restrict__ Qf) {
    __shared__ bf16_t lds[65536];
    const int NT = 32;
    int tid = threadIdx.x, lane = tid & 63, wid = tid >> 6;
    int wr = wid >> 2, wc = wid & 3;
    int nwg = gridDim.x;
    int bid = blockIdx.x;
    int lid = (bid & 7) * (nwg >> 3) + (bid >> 3);   // XCD-contiguous remap
    int by = lid % nby;
    int t2_ = lid / nby;
    int bx = t2_ % nbx;
    int z = t2_ / nbx;
    const bf16_t* Gt = Gint + (long long)z * sG + (long long)(F32A ? by : bx) * 256 * 2048;
    const float* Ft = Fsrc + (long long)z * sF + (long long)(F32A ? bx : by) * 256 * 1024;
    const int FOFF = F32A ? 0 : 16384;   // f32 operand region (A at 0, B at 16384)
    const int GOFF = F32A ? 16384 : 0;   // glds operand region
    {   // prologue: stage tiles 0,1
        f32x4 v[4];
        ldf32(Ft, tid, v);
        wrsplit(lds + FOFF, tid, v);
        ldf32(Ft + 32, tid, v);
        wrsplit(lds + 32768 + FOFF, tid, v);
        stageG(Gt, lds + GOFF, tid);
        stageG(Gt + 64, lds + 32768 + GOFF, tid);
        asm volatile("s_waitcnt lgkmcnt(0) vmcnt(0)" ::: "memory");
        SB0;
        __builtin_amdgcn_s_barrier();
    }
    f32x4 acc[8][4] = {};
    int l15 = lane & 15, l4 = lane >> 4;
    for (int t = 0; t < NT; ++t) {
        bf16_t* buf = lds + (size_t)(t & 1) * 32768;
        bf16_t* bufB = buf + 16384;
        bool st = (t + 2 < NT);
        f32x4 v[4];
        if (st) ldf32(Ft + (t + 2) * 32, tid, v);
        SB0;
        // ---- P0: read B all + A m0,m1; MFMA m0,m1 ----
        bf16x8 bh[4], bl[4], ahA[2], alA[2];
#pragma unroll
        for (int n = 0; n < 4; ++n) {
            int rB = wc * 64 + n * 16 + l15;
            bh[n] = *(const bf16x8*)(bufB + lch(rB, l4));
            bl[n] = *(const bf16x8*)(bufB + lch(rB, 4 + l4));
        }
#pragma unroll
        for (int i = 0; i < 2; ++i) {
            int rA = wr * 128 + i * 16 + l15;
            ahA[i] = *(const bf16x8*)(buf + lch(rA, l4));
            alA[i] = *(const bf16x8*)(buf + lch(rA, 4 + l4));
        }
        P_PRE;
#pragma unroll
        for (int i = 0; i < 2; ++i)
#pragma unroll
            for (int n = 0; n < 4; ++n) {
                f32x4 a = acc[i][n];
                a = MFMA_BF16(ahA[i], bh[n], a, 0, 0, 0);
                a = MFMA_BF16(ahA[i], bl[n], a, 0, 0, 0);
                a = MFMA_BF16(alA[i], bh[n], a, 0, 0, 0);
                acc[i][n] = a;
            }
        P_POST;
        // ---- P1: read A m2..m5; MFMA m2,m3 ----
        bf16x8 ahB[2], alB[2], ahC[2], alC[2];
#pragma unroll
        for (int i = 0; i < 2; ++i) {
            int rA = wr * 128 + (2 + i) * 16 + l15;
            ahB[i] = *(const bf16x8*)(buf + lch(rA, l4));
            alB[i] = *(const bf16x8*)(buf + lch(rA, 4 + l4));
        }
#pragma unroll
        for (int i = 0; i < 2; ++i) {
            int rA = wr * 128 + (4 + i) * 16 + l15;
            ahC[i] = *(const bf16x8*)(buf + lch(rA, l4));
            alC[i] = *(const bf16x8*)(buf + lch(rA, 4 + l4));
        }
        P_PRE;
#pragma unroll
        for (int i = 0; i < 2; ++i)
#pragma unroll
            for (int n = 0; n < 4; ++n) {
                f32x4 a = acc[2 + i][n];
                a = MFMA_BF16(ahB[i], bh[n], a, 0, 0, 0);
                a = MFMA_BF16(ahB[i], bl[n], a, 0, 0, 0);
                a = MFMA_BF16(alB[i], bh[n], a, 0, 0, 0);
                acc[2 + i][n] = a;
            }
        P_POST;
        // ---- P2: read A m6,m7; glds-stage(t+2) if F32A (B region); MFMA m4,m5 ----
        bf16x8 ahD[2], alD[2];
#pragma unroll
        for (int i = 0; i < 2; ++i) {
            int rA = wr * 128 + (6 + i) * 16 + l15;
            ahD[i] = *(const bf16x8*)(buf + lch(rA, l4));
            alD[i] = *(const bf16x8*)(buf + lch(rA, 4 + l4));
        }
        if (st && F32A) stageG(Gt + (long long)(t + 2) * 64, buf + GOFF, tid);
        P_PRE;
#pragma unroll
        for (int i = 0; i < 2; ++i)
#pragma unroll
            for (int n = 0; n < 4; ++n) {
                f32x4 a = acc[4 + i][n];
                a = MFMA_BF16(ahC[i], bh[n], a, 0, 0, 0);
                a = MFMA_BF16(ahC[i], bl[n], a, 0, 0, 0);
                a = MFMA_BF16(alC[i], bh[n], a, 0, 0, 0);
                acc[4 + i][n] = a;
            }
        P_POST;
        // ---- P3: glds-stage(t+2) if !F32A (A region); convert+write f32(t+2);
        //          MFMA m6,m7; drain; barrier ----
        if (st && !F32A) stageG(Gt + (long long)(t + 2) * 64, buf + GOFF, tid);
        if (st) wrsplit(buf + FOFF, tid, v);   // compiler inserts counted vmcnt for v
        __builtin_amdgcn_s_setprio(1);
#pragma unroll
        for (int i = 0; i < 2; ++i)
#pragma unroll
            for (int n = 0; n < 4; ++n) {
                f32x4 a = acc[6 + i][n];
                a = MFMA_BF16(ahD[i], bh[n], a, 0, 0, 0);
                a = MFMA_BF16(ahD[i], bl[n], a, 0, 0, 0);
                a = MFMA_BF16(alD[i], bh[n], a, 0, 0, 0);
                acc[6 + i][n] = a;
            }
        __builtin_amdgcn_s_setprio(0);
        SB0;
        asm volatile("s_waitcnt lgkmcnt(0)" ::: "memory");
        SB0;
        if (st) {
            asm volatile("s_waitcnt vmcnt(4)" ::: "memory");
        } else {
            asm volatile("s_waitcnt vmcnt(0)" ::: "memory");
        }
        SB0;
        __builtin_amdgcn_s_barrier();
    }
    int r0 = bx * 256 + wr * 128 + (l4 << 2);
    int c0 = by * 256 + wc * 64 + l15;
    const int* mrow = (EPI == 0) ? (Mk + (long long)z * 1048576ll) : nullptr;
#pragma unroll
    for (int m = 0; m < 8; ++m)
#pragma unroll
        for (int n = 0; n < 4; ++n)
#pragma unroll
            for (int j = 0; j < 4; ++j) {
                int r = r0 + m * 16 + j;
                int c = c0 + n * 16;
                float v = acc[m][n][j];
                if (EPI == 0) {
                    int mv = mrow[(long long)r * 1024 + c];
                    Cs[(long long)z * sC + (long long)r * 1024 + c] = mv ? v : -3.0e38f;
                } else {
                    float rep;
                    bf16_t hb = to_bf16_rne(v, rep);
                    float res = v - rep;
                    float rep2;
                    bf16_t lb = to_bf16_rne(res, rep2);
                    long long rb = (long long)r * 2048 + ((c >> 5) << 6) + (c & 31);
                    Qint[rb] = hb;
                    Qint[rb + 32] = lb;
                    Qf[(long long)r * 1024 + c] = (_Float16)v;
                }
            }
}

// ---------- 256x256 dbuf f16 GEMM, 4-phase interleave (BK=64) — round-7 build ----------
template <int EPI>
__global__ __launch_bounds__(512, 2) void gemm_f16_256(
    const _Float16* __restrict__ A1, const _Float16* __restrict__ A2,
    const _Float16* __restrict__ B,
    long long ldA, long long ldB, long long sA, long long sB, long long sC,
    int NT, int swt, int nbx, int nby,
    _Float16* __restrict__ Cm, float* __restrict__ Co) {
    __shared__ _Float16 lds[65536];
    int tid = threadIdx.x, lane = tid & 63, wid = tid >> 6;
    int wr = wid >> 2, wc = wid & 3;
    int nwg = gridDim.x;
    int bid = blockIdx.x;
    int lid = (bid & 7) * (nwg >> 3) + (bid >> 3);
    int by = lid % nby;
    int t2_ = lid / nby;
    int bx = t2_ % nbx;
    int z = t2_ / nbx;
    const _Float16* A1t = A1 + (long long)z * sA + (long long)bx * 256 * ldA;
    const _Float16* A2t = A2 + (long long)bx * 256 * ldA;
    const _Float16* Bt = B + (long long)z * sB + (long long)by * 256 * ldB;
    stage2h((0 < swt) ? A1t : A2t, ldA, Bt, ldB, lds, tid);
    stage2h((1 < swt) ? A1t + 64 : A2t + (long long)(1 - swt) * 64, ldA, Bt + 64, ldB,
            lds + 32768, tid);
    f32x4 acc[8][4] = {};
    int l15 = lane & 15, l4 = lane >> 4;
    asm volatile("s_waitcnt vmcnt(8)" ::: "memory");
    SB0;
    __builtin_amdgcn_s_barrier();
    for (int t = 0; t < NT; ++t) {
        _Float16* buf = lds + (size_t)(t & 1) * 32768;
        _Float16* bufB = buf + 16384;
        int tt = t + 2;
        bool st = (tt < NT);
        const _Float16* gA2 =
            (tt < swt) ? A1t + (long long)tt * 64 : A2t + (long long)(tt - swt) * 64;
        const _Float16* gB2 = Bt + (long long)tt * 64;
        // ---- P0 ----
        f16x8 bfr[4][2], aA[2][2];
#pragma unroll
        for (int n = 0; n < 4; ++n) {
            int rB = wc * 64 + n * 16 + l15;
#pragma unroll
            for (int ks = 0; ks < 2; ++ks)
                bfr[n][ks] = *(const f16x8*)(bufB + lch(rB, ks * 4 + l4));
        }
#pragma unroll
        for (int i = 0; i < 2; ++i) {
            int rA = wr * 128 + i * 16 + l15;
#pragma unroll
            for (int ks = 0; ks < 2; ++ks)
                aA[i][ks] = *(const f16x8*)(buf + lch(rA, ks * 4 + l4));
        }
        P_PRE;
#pragma unroll
        for (int i = 0; i < 2; ++i)
#pragma unroll
            for (int n = 0; n < 4; ++n) {
                f32x4 vv = acc[i][n];
                vv = MFMA_F16(aA[i][0], bfr[n][0], vv, 0, 0, 0);
                vv = MFMA_F16(aA[i][1], bfr[n][1], vv, 0, 0, 0);
                acc[i][n] = vv;
            }
        P_POST;
        // ---- P1 ----
        f16x8 aB[2][2], aC[2][2];
#pragma unroll
        for (int i = 0; i < 2; ++i) {
            int rA = wr * 128 + (2 + i) * 16 + l15;
#pragma unroll
            for (int ks = 0; ks < 2; ++ks)
                aB[i][ks] = *(const f16x8*)(buf + lch(rA, ks * 4 + l4));
        }
#pragma unroll
        for (int i = 0; i < 2; ++i) {
            int rA = wr * 128 + (4 + i) * 16 + l15;
#pragma unroll
            for (int ks = 0; ks < 2; ++ks)
                aC[i][ks] = *(const f16x8*)(buf + lch(rA, ks * 4 + l4));
        }
        P_PRE;
#pragma unroll
        for (int i = 0; i < 2; ++i)
#pragma unroll
            for (int n = 0; n < 4; ++n) {
                f32x4 vv = acc[2 + i][n];
                vv = MFMA_F16(aB[i][0], bfr[n][0], vv, 0, 0, 0);
                vv = MFMA_F16(aB[i][1], bfr[n][1], vv, 0, 0, 0);
                acc[2 + i][n] = vv;
            }
        P_POST;
        // ---- P2 ----
        f16x8 aD[2][2];
#pragma unroll
        for (int i = 0; i < 2; ++i) {
            int rA = wr * 128 + (6 + i) * 16 + l15;
#pragma unroll
            for (int ks = 0; ks < 2; ++ks)
                aD[i][ks] = *(const f16x8*)(buf + lch(rA, ks * 4 + l4));
        }
        if (st) stageB4h(gB2, ldB, buf, tid);
        P_PRE;
#pragma unroll
        for (int i = 0; i < 2; ++i)
#pragma unroll
            for (int n = 0; n < 4; ++n) {
                f32x4 vv = acc[4 + i][n];
                vv = MFMA_F16(aC[i][0], bfr[n][0], vv, 0, 0, 0);
                vv = MFMA_F16(aC[i][1], bfr[n][1], vv, 0, 0, 0);
                acc[4 + i][n] = vv;
            }
        P_POST;
        // ---- P3 ----
        if (st) stageA4h(gA2, ldA, buf, tid);
        __builtin_amdgcn_s_setprio(1);
#pragma unroll
        for (int i = 0; i < 2; ++i)
#pragma unroll
            for (int n = 0; n < 4; ++n) {
                f32x4 vv = acc[6 + i][n];
                vv = MFMA_F16(aD[i][0], bfr[n][0], vv, 0, 0, 0);
                vv = MFMA_F16(aD[i][1], bfr[n][1], vv, 0, 0, 0);
                acc[6 + i][n] = vv;
            }
        __builtin_amdgcn_s_setprio(0);
        SB0;
        if (t + 2 < NT) {
            asm volatile("s_waitcnt vmcnt(8)" ::: "memory");
        } else if (t + 1 < NT) {
            asm volatile("s_waitcnt vmcnt(0)" ::: "memory");
        }
        SB0;
        __builtin_amdgcn_s_barrier();
    }
    int r0 = bx * 256 + wr * 128 + (l4 << 2);
    int c0 = by * 256 + wc * 64 + l15;
#pragma unroll
    for (int m = 0; m < 8; ++m)
#pragma unroll
        for (int n = 0; n < 4; ++n)
#pragma unroll
            for (int j = 0; j < 4; ++j) {
                int r = r0 + m * 16 + j;
                int c = c0 + n * 16;
                float v = acc[m][n][j];
                if (EPI == 0) {
                    Cm[(long long)z * sC + (long long)r * 1024 + c] = (_Float16)v;
                } else {
                    Co[(long long)r * 1024 + c] = tanhf(v);
                }
            }
}

// ---------- launch ----------

extern "C" void kernel_launch(void* const* d_in, const int* in_sizes, int n_in,
                              void* d_out, int out_size, void* d_ws, size_t ws_size,
                              hipStream_t stream) {
    const float* query = (const float*)d_in[0];
    const float* ctx = (const float*)d_in[1];
    const int* mask = (const int*)d_in[2];
    const float* Win = (const float*)d_in[3];
    const float* Wout = (const float*)d_in[4];
    float* outp = (float*)d_out;

    const long long MB = 1048576ll;
    // footprint: exactly 16G MiB (weights overlaid into dead slab regions).
    int G = 1;
    if ((long long)ws_size >= 512 * MB) G = 32;
    else if ((long long)ws_size >= 256 * MB) G = 16;
    else if ((long long)ws_size >= 128 * MB) G = 8;
    else if ((long long)ws_size >= 64 * MB) G = 4;
    else if ((long long)ws_size >= 32 * MB) G = 2;

    char* p = (char*)d_ws;
    const long long R = (long long)G * 1024;       // rows per chunk
    bf16_t* qint = (bf16_t*)p; p += 4 * G * MB;    // [R][2048] interleaved
    _Float16* qf = (_Float16*)p; p += 2 * G * MB;  // [R][1024]
    _Float16* ctxT = (_Float16*)p; p += 2 * G * MB;
    _Float16* wf = (_Float16*)p; p += 2 * G * MB;
    _Float16* mixf = (_Float16*)p; p += 2 * G * MB;
    float* scores = (float*)p;                     // 4G MiB
    bf16_t* win_int = (bf16_t*)scores;             // 4 MiB; dead before GEMM2 writes
    _Float16* woutf = (_Float16*)qint;             // 4 MiB; qint dead after GEMM2

    const long long LD = 1048576ll;  // 1024*1024 elements

    for (int b0 = 0; b0 < 32; b0 += G) {
        const float* qsrc = query + (long long)b0 * LD;
        const float* csrc = ctx + (long long)b0 * LD;
        // Win split into head of scores slab (GEMM2 overwrites later)
        split_int_k<<<1024, 256, 0, stream>>>(Win, win_int, 262144ll);
        // GEMM1: q = query @ Win^T (A = raw f32 query, fused split; B = win glds)
        gemm_x3_256<1, true><<<16 * G, 512, 0, stream>>>(
            win_int, qsrc, nullptr, 0, 0, 0, 4 * G, 4, nullptr, qint, qf);
        // ctx transpose only (bf16 split fused into GEMM2)
        transpose_ctx_k<<<dim3(32, 32, G), dim3(32, 8, 1), 0, stream>>>(csrc, ctxT);
        // GEMM2: scores = q @ ctx^T (A = qint glds; B = raw f32 ctx, fused split;
        //        epilogue applies mask sentinel)
        gemm_x3_256<0, false><<<16 * G, 512, 0, stream>>>(
            qint, csrc, mask + (long long)b0 * LD,
            2097152ll, 1048576ll, 1048576ll, 4, 4, scores, nullptr, nullptr);
        // softmax on sentinel-masked scores (mask not re-read)
        masked_softmax_k<<<(int)R, 256, 0, stream>>>(scores, wf);
        // Wout cast into head of qint (dead after GEMM2)
        cast_f16_k<<<2048, 256, 0, stream>>>(Wout, woutf, 524288ll);
        // GEMM3: mix = w @ ctxT^T (f16)
        gemm_f16_256<0><<<16 * G, 512, 0, stream>>>(
            wf, wf, ctxT, 1024ll, 1024ll, 1048576ll, 1048576ll, 1048576ll,
            16, 1 << 20, 4, 4, mixf, nullptr);
        // GEMM4: out = tanh(mix @ W1^T + q @ W2^T), K=2048, A-switch at tile 16
        gemm_f16_256<1><<<16 * G, 512, 0, stream>>>(
            mixf, qf, woutf, 1024ll, 2048ll, 0, 0, 0,
            32, 16, 4 * G, 4, nullptr, outp + (long long)b0 * LD);
    }
}

// Round 11
// 778.157 us; speedup vs baseline: 1.1532x; 1.0041x over previous
//
#include <hip/hip_runtime.h>
#include <math.h>

typedef __bf16 bf16_t;
typedef __bf16 bf16x4 __attribute__((ext_vector_type(4)));
typedef __bf16 bf16x8 __attribute__((ext_vector_type(8)));
typedef _Float16 f16x4 __attribute__((ext_vector_type(4)));
typedef _Float16 f16x8 __attribute__((ext_vector_type(8)));
typedef float f32x4 __attribute__((ext_vector_type(4)));
typedef int i32x4 __attribute__((ext_vector_type(4)));

#define MFMA_BF16 __builtin_amdgcn_mfma_f32_16x16x32_bf16
#define MFMA_F16  __builtin_amdgcn_mfma_f32_16x16x32_f16
#define SB0 __builtin_amdgcn_sched_barrier(0)

// phase sync: barrier, drain own ds reads, pin, boost
#define P_PRE                                         \
    __builtin_amdgcn_sched_barrier(0);                \
    __builtin_amdgcn_s_barrier();                     \
    asm volatile("s_waitcnt lgkmcnt(0)" ::: "memory");\
    __builtin_amdgcn_sched_barrier(0);                \
    __builtin_amdgcn_s_setprio(1)
#define P_POST                                        \
    __builtin_amdgcn_s_setprio(0);                    \
    __builtin_amdgcn_sched_barrier(0);                \
    __builtin_amdgcn_s_barrier()

// ---------- helpers ----------

__device__ __forceinline__ bf16_t to_bf16_rne(float x, float& rep) {
    unsigned u = __builtin_bit_cast(unsigned, x);
    unsigned r = u + 0x7fffu + ((u >> 16) & 1u);
    unsigned short h = (unsigned short)(r >> 16);
    rep = __builtin_bit_cast(float, ((unsigned)h) << 16);
    return __builtin_bit_cast(bf16_t, h);
}

__device__ __forceinline__ void g2l16(const void* g, void* l) {
    __builtin_amdgcn_global_load_lds(
        (const __attribute__((address_space(1))) unsigned int*)g,
        (__attribute__((address_space(3))) unsigned int*)l, 16, 0, 0);
}

// swizzled element offset of 16B-chunk (row r in 0..255, chunk j in 0..7);
// rows are 128B. j ^= (r&7): involution, applied on pre-swizzled glds
// source AND on every ds_read. 16-row read spans -> 2-way (free) aliasing.
__device__ __forceinline__ int lch(int r, int j) {
    return (r * 8 + (j ^ (r & 7))) * 8;
}

// stage A half-tile (256 rows x 128B) into buf[0:16384); 4 loads/thread
template <typename T>
__device__ __forceinline__ void stageA4(const T* __restrict__ gA, long long ldA,
                                        T* buf, int tid) {
    int wid = tid >> 6, lane = tid & 63;
#pragma unroll
    for (int i = 0; i < 4; ++i) {
        int cb = i * 512 + wid * 64;
        int c = cb + lane;
        int r = c >> 3, j = (c & 7) ^ (r & 7);
        g2l16(gA + (long long)r * ldA + j * 8, buf + (size_t)cb * 8);
    }
}

// stage B half-tile into buf[16384:32768); 4 loads/thread
template <typename T>
__device__ __forceinline__ void stageB4(const T* __restrict__ gB, long long ldB,
                                        T* buf, int tid) {
    int wid = tid >> 6, lane = tid & 63;
#pragma unroll
    for (int i = 0; i < 4; ++i) {
        int cb = i * 512 + wid * 64;
        int c = cb + lane;
        int r = c >> 3, j = (c & 7) ^ (r & 7);
        g2l16(gB + (long long)r * ldB + j * 8, buf + 16384 + (size_t)cb * 8);
    }
}

template <typename T>
__device__ __forceinline__ void stage2(const T* __restrict__ gA, long long ldA,
                                       const T* __restrict__ gB, long long ldB,
                                       T* buf, int tid) {
    stageA4(gA, ldA, buf, tid);
    stageB4(gB, ldB, buf, tid);
}

// ---------- elementwise prep kernels ----------

// f32 [rows][1024] -> interleaved bf16 hi/lo: row stride 2048, 32-k blocks [32 hi|32 lo]
__global__ __launch_bounds__(256) void split_int_k(const float* __restrict__ in,
                                                   bf16_t* __restrict__ out,
                                                   long long n4) {
    long long i = (long long)blockIdx.x * 256 + threadIdx.x;
    if (i >= n4) return;
    f32x4 v = ((const f32x4*)in)[i];
    bf16x4 hv, lv;
#pragma unroll
    for (int j = 0; j < 4; ++j) {
        float rep;
        hv[j] = to_bf16_rne(v[j], rep);
        float res = v[j] - rep;
        float rep2;
        lv[j] = to_bf16_rne(res, rep2);
    }
    long long row = i >> 8;
    int k = (int)(i & 255) * 4;
    long long base = row * 2048 + ((k >> 5) << 6) + (k & 31);
    *(bf16x4*)(out + base) = hv;
    *(bf16x4*)(out + base + 32) = lv;
}

__global__ __launch_bounds__(256) void cast_f16_k(const float* __restrict__ in,
                                                  _Float16* __restrict__ o, long long n4) {
    long long i = (long long)blockIdx.x * 256 + threadIdx.x;
    if (i >= n4) return;
    f32x4 v = ((const f32x4*)in)[i];
    f16x4 h;
#pragma unroll
    for (int j = 0; j < 4; ++j) h[j] = (_Float16)v[j];
    ((f16x4*)o)[i] = h;
}

// fused: ctx chunk [G][1024][1024] f32 -> ctx_int (interleaved hi/lo bf16, rows 2048)
//        AND ctxT [G][1024(d)][1024(k)] f16   (reads ctx ONCE)
__global__ __launch_bounds__(256) void prep_ctx_k(const float* __restrict__ ctx,
                                                  bf16_t* __restrict__ ctx_int,
                                                  _Float16* __restrict__ ctxT) {
    __shared__ _Float16 tl[32][33];
    int b = blockIdx.z;
    int k0 = blockIdx.x * 32, d0 = blockIdx.y * 32;
    const float* src = ctx + ((long long)b * 1024 + k0) * 1024 + d0;
    int x = threadIdx.x, y = threadIdx.y;  // 32 x 8
#pragma unroll
    for (int i = 0; i < 4; ++i) {
        int k = y + i * 8;
        float v = src[(long long)k * 1024 + x];
        float rep;
        bf16_t hb = to_bf16_rne(v, rep);
        float rep2;
        bf16_t lb = to_bf16_rne(v - rep, rep2);
        long long rb = ((long long)b * 1024 + k0 + k) * 2048 + d0 * 2 + x;
        ctx_int[rb] = hb;
        ctx_int[rb + 32] = lb;
        tl[x][k] = (_Float16)v;
    }
    __syncthreads();
    _Float16* dst = ctxT + ((long long)b * 1024 + d0) * 1024 + k0;
#pragma unroll
    for (int i = 0; i < 4; ++i) {
        int dd = y + i * 8;
        dst[(long long)dd * 1024 + x] = tl[dd][x];
    }
}

// softmax over sentinel-masked scores (-3e38 = masked); no mask re-read.
// w_k = exp(s_k - max)/sum ; all-masked row -> zeros.
__global__ __launch_bounds__(256) void masked_softmax_k(const float* __restrict__ s,
                                                        _Float16* __restrict__ w) {
    long long row = blockIdx.x;
    const f32x4* sr = (const f32x4*)(s + row * 1024);
    f16x4* wr_ = (f16x4*)(w + row * 1024);
    int t = threadIdx.x;
    int lane = t & 63, wid = t >> 6;
    f32x4 v = sr[t];
    float mx = fmaxf(fmaxf(v[0], v[1]), fmaxf(v[2], v[3]));
#pragma unroll
    for (int off = 32; off; off >>= 1) mx = fmaxf(mx, __shfl_xor(mx, off));
    __shared__ float rm[4], rs[4];
    if (!lane) rm[wid] = mx;
    __syncthreads();
    mx = fmaxf(fmaxf(rm[0], rm[1]), fmaxf(rm[2], rm[3]));
    float sum = 0.f;
    f32x4 e;
#pragma unroll
    for (int i = 0; i < 4; ++i) {
        e[i] = expf(v[i] - mx);   // masked entry: -3e38 - mx -> 0
        sum += e[i];
    }
#pragma unroll
    for (int off = 32; off; off >>= 1) sum += __shfl_xor(sum, off);
    if (!lane) rs[wid] = sum;
    __syncthreads();
    sum = rs[0] + rs[1] + rs[2] + rs[3];
    float inv = (mx < -1.0e38f) ? 0.f : 1.0f / sum;
    f16x4 o;
#pragma unroll
    for (int i = 0; i < 4; ++i) o[i] = (_Float16)(e[i] * inv);
    wr_[t] = o;
}

// ---------- 256x256 dbuf bf16x3 GEMM, 4-phase interleave (round-7 build) ----------
// A,B: interleaved hi/lo pair layout, rows of 2048 elements, K=1024 (BK=32).
// Per K-tile: P0{read B + m01 | MFMA m01} P1{read m2345 | MFMA m23}
// P2{read m67, stage B(t+2) | MFMA m45} P3{stage A(t+2), vmcnt(8) | MFMA m67}.
// EPI 0: sentinel-masked f32 scores (reads Mk). EPI 1: qint interleaved + qf f16.
template <int EPI>
__global__ __launch_bounds__(512, 2) void gemm_x3_256(
    const bf16_t* __restrict__ Aint, const bf16_t* __restrict__ Bint,
    const int* __restrict__ Mk,
    long long sA, long long sB, long long sC, int nbx, int nby,
    float* __restrict__ Cs, bf16_t* __restrict__ Qint, _Float16* __restrict__ Qf) {
    __shared__ bf16_t lds[65536];
    const int NT = 32;
    int tid = threadIdx.x, lane = tid & 63, wid = tid >> 6;
    int wr = wid >> 2, wc = wid & 3;
    int nwg = gridDim.x;
    int bid = blockIdx.x;
    int lid = (bid & 7) * (nwg >> 3) + (bid >> 3);   // XCD-contiguous remap
    int by = lid % nby;
    int t2_ = lid / nby;
    int bx = t2_ % nbx;
    int z = t2_ / nbx;
    const bf16_t* At = Aint + (long long)z * sA + (long long)bx * 256 * 2048;
    const bf16_t* Bt = Bint + (long long)z * sB + (long long)by * 256 * 2048;
    stage2(At, 2048ll, Bt, 2048ll, lds, tid);
    stage2(At + 64, 2048ll, Bt + 64, 2048ll, lds + 32768, tid);
    f32x4 acc[8][4] = {};
    int l15 = lane & 15, l4 = lane >> 4;
    asm volatile("s_waitcnt vmcnt(8)" ::: "memory");
    SB0;
    __builtin_amdgcn_s_barrier();
    for (int t = 0; t < NT; ++t) {
        bf16_t* buf = lds + (size_t)(t & 1) * 32768;
        bf16_t* bufB = buf + 16384;
        const bf16_t* At2 = At + (long long)(t + 2) * 64;
        const bf16_t* Bt2 = Bt + (long long)(t + 2) * 64;
        bool st = (t + 2 < NT);
        // ---- P0: read B all + A m0,m1; MFMA m0,m1 ----
        bf16x8 bh[4], bl[4], ahA[2], alA[2];
#pragma unroll
        for (int n = 0; n < 4; ++n) {
            int rB = wc * 64 + n * 16 + l15;
            bh[n] = *(const bf16x8*)(bufB + lch(rB, l4));
            bl[n] = *(const bf16x8*)(bufB + lch(rB, 4 + l4));
        }
#pragma unroll
        for (int i = 0; i < 2; ++i) {
            int rA = wr * 128 + i * 16 + l15;
            ahA[i] = *(const bf16x8*)(buf + lch(rA, l4));
            alA[i] = *(const bf16x8*)(buf + lch(rA, 4 + l4));
        }
        P_PRE;
#pragma unroll
        for (int i = 0; i < 2; ++i)
#pragma unroll
            for (int n = 0; n < 4; ++n) {
                f32x4 a = acc[i][n];
                a = MFMA_BF16(ahA[i], bh[n], a, 0, 0, 0);
                a = MFMA_BF16(ahA[i], bl[n], a, 0, 0, 0);
                a = MFMA_BF16(alA[i], bh[n], a, 0, 0, 0);
                acc[i][n] = a;
            }
        P_POST;
        // ---- P1: read A m2..m5; MFMA m2,m3 ----
        bf16x8 ahB[2], alB[2], ahC[2], alC[2];
#pragma unroll
        for (int i = 0; i < 2; ++i) {
            int rA = wr * 128 + (2 + i) * 16 + l15;
            ahB[i] = *(const bf16x8*)(buf + lch(rA, l4));
            alB[i] = *(const bf16x8*)(buf + lch(rA, 4 + l4));
        }
#pragma unroll
        for (int i = 0; i < 2; ++i) {
            int rA = wr * 128 + (4 + i) * 16 + l15;
            ahC[i] = *(const bf16x8*)(buf + lch(rA, l4));
            alC[i] = *(const bf16x8*)(buf + lch(rA, 4 + l4));
        }
        P_PRE;
#pragma unroll
        for (int i = 0; i < 2; ++i)
#pragma unroll
            for (int n = 0; n < 4; ++n) {
                f32x4 a = acc[2 + i][n];
                a = MFMA_BF16(ahB[i], bh[n], a, 0, 0, 0);
                a = MFMA_BF16(ahB[i], bl[n], a, 0, 0, 0);
                a = MFMA_BF16(alB[i], bh[n], a, 0, 0, 0);
                acc[2 + i][n] = a;
            }
        P_POST;
        // ---- P2: read A m6,m7; stage B(t+2); MFMA m4,m5 ----
        bf16x8 ahD[2], alD[2];
#pragma unroll
        for (int i = 0; i < 2; ++i) {
            int rA = wr * 128 + (6 + i) * 16 + l15;
            ahD[i] = *(const bf16x8*)(buf + lch(rA, l4));
            alD[i] = *(const bf16x8*)(buf + lch(rA, 4 + l4));
        }
        if (st) stageB4(Bt2, 2048ll, buf, tid);
        P_PRE;
#pragma unroll
        for (int i = 0; i < 2; ++i)
#pragma unroll
            for (int n = 0; n < 4; ++n) {
                f32x4 a = acc[4 + i][n];
                a = MFMA_BF16(ahC[i], bh[n], a, 0, 0, 0);
                a = MFMA_BF16(ahC[i], bl[n], a, 0, 0, 0);
                a = MFMA_BF16(alC[i], bh[n], a, 0, 0, 0);
                acc[4 + i][n] = a;
            }
        P_POST;
        // ---- P3: stage A(t+2); vmcnt(8); MFMA m6,m7 ----
        if (st) stageA4(At2, 2048ll, buf, tid);
        __builtin_amdgcn_s_setprio(1);
#pragma unroll
        for (int i = 0; i < 2; ++i)
#pragma unroll
            for (int n = 0; n < 4; ++n) {
                f32x4 a = acc[6 + i][n];
                a = MFMA_BF16(ahD[i], bh[n], a, 0, 0, 0);
                a = MFMA_BF16(ahD[i], bl[n], a, 0, 0, 0);
                a = MFMA_BF16(alD[i], bh[n], a, 0, 0, 0);
                acc[6 + i][n] = a;
            }
        __builtin_amdgcn_s_setprio(0);
        SB0;
        if (t + 2 < NT) {
            asm volatile("s_waitcnt vmcnt(8)" ::: "memory");
        } else if (t + 1 < NT) {
            asm volatile("s_waitcnt vmcnt(0)" ::: "memory");
        }
        SB0;
        __builtin_amdgcn_s_barrier();
    }
    int r0 = bx * 256 + wr * 128 + (l4 << 2);
    int c0 = by * 256 + wc * 64 + l15;
    const int* mrow = (EPI == 0) ? (Mk + (long long)z * 1048576ll) : nullptr;
#pragma unroll
    for (int m = 0; m < 8; ++m)
#pragma unroll
        for (int n = 0; n < 4; ++n)
#pragma unroll
            for (int j = 0; j < 4; ++j) {
                int r = r0 + m * 16 + j;
                int c = c0 + n * 16;
                float v = acc[m][n][j];
                if (EPI == 0) {
                    int mv = mrow[(long long)r * 1024 + c];
                    Cs[(long long)z * sC + (long long)r * 1024 + c] = mv ? v : -3.0e38f;
                } else {
                    float rep;
                    bf16_t hb = to_bf16_rne(v, rep);
                    float res = v - rep;
                    float rep2;
                    bf16_t lb = to_bf16_rne(res, rep2);
                    long long rb = (long long)r * 2048 + ((c >> 5) << 6) + (c & 31);
                    Qint[rb] = hb;
                    Qint[rb + 32] = lb;
                    Qf[(long long)r * 1024 + c] = (_Float16)v;
                }
            }
}

// ---------- 256x256 dbuf f16 GEMM, 4-phase interleave (BK=64, round-7 build) ----------
// A rows K-contig (ldA), optional A-source switch at tile swt. B rows K-contig.
// EPI 0: f16 out (ld 1024, +z*sC). EPI 1: f32 tanh out (ld 1024).
template <int EPI>
__global__ __launch_bounds__(512, 2) void gemm_f16_256(
    const _Float16* __restrict__ A1, const _Float16* __restrict__ A2,
    const _Float16* __restrict__ B,
    long long ldA, long long ldB, long long sA, long long sB, long long sC,
    int NT, int swt, int nbx, int nby,
    _Float16* __restrict__ Cm, float* __restrict__ Co) {
    __shared__ _Float16 lds[65536];
    int tid = threadIdx.x, lane = tid & 63, wid = tid >> 6;
    int wr = wid >> 2, wc = wid & 3;
    int nwg = gridDim.x;
    int bid = blockIdx.x;
    int lid = (bid & 7) * (nwg >> 3) + (bid >> 3);
    int by = lid % nby;
    int t2_ = lid / nby;
    int bx = t2_ % nbx;
    int z = t2_ / nbx;
    const _Float16* A1t = A1 + (long long)z * sA + (long long)bx * 256 * ldA;
    const _Float16* A2t = A2 + (long long)bx * 256 * ldA;
    const _Float16* Bt = B + (long long)z * sB + (long long)by * 256 * ldB;
    stage2((0 < swt) ? A1t : A2t, ldA, Bt, ldB, lds, tid);
    stage2((1 < swt) ? A1t + 64 : A2t + (long long)(1 - swt) * 64, ldA, Bt + 64, ldB,
           lds + 32768, tid);
    f32x4 acc[8][4] = {};
    int l15 = lane & 15, l4 = lane >> 4;
    asm volatile("s_waitcnt vmcnt(8)" ::: "memory");
    SB0;
    __builtin_amdgcn_s_barrier();
    for (int t = 0; t < NT; ++t) {
        _Float16* buf = lds + (size_t)(t & 1) * 32768;
        _Float16* bufB = buf + 16384;
        int tt = t + 2;
        bool st = (tt < NT);
        const _Float16* gA2 =
            (tt < swt) ? A1t + (long long)tt * 64 : A2t + (long long)(tt - swt) * 64;
        const _Float16* gB2 = Bt + (long long)tt * 64;
        // ---- P0: read B all + A m0,m1; MFMA m0,m1 ----
        f16x8 bfr[4][2], aA[2][2];
#pragma unroll
        for (int n = 0; n < 4; ++n) {
            int rB = wc * 64 + n * 16 + l15;
#pragma unroll
            for (int ks = 0; ks < 2; ++ks)
                bfr[n][ks] = *(const f16x8*)(bufB + lch(rB, ks * 4 + l4));
        }
#pragma unroll
        for (int i = 0; i < 2; ++i) {
            int rA = wr * 128 + i * 16 + l15;
#pragma unroll
            for (int ks = 0; ks < 2; ++ks)
                aA[i][ks] = *(const f16x8*)(buf + lch(rA, ks * 4 + l4));
        }
        P_PRE;
#pragma unroll
        for (int i = 0; i < 2; ++i)
#pragma unroll
            for (int n = 0; n < 4; ++n) {
                f32x4 v = acc[i][n];
                v = MFMA_F16(aA[i][0], bfr[n][0], v, 0, 0, 0);
                v = MFMA_F16(aA[i][1], bfr[n][1], v, 0, 0, 0);
                acc[i][n] = v;
            }
        P_POST;
        // ---- P1: read A m2..m5; MFMA m2,m3 ----
        f16x8 aB[2][2], aC[2][2];
#pragma unroll
        for (int i = 0; i < 2; ++i) {
            int rA = wr * 128 + (2 + i) * 16 + l15;
#pragma unroll
            for (int ks = 0; ks < 2; ++ks)
                aB[i][ks] = *(const f16x8*)(buf + lch(rA, ks * 4 + l4));
        }
#pragma unroll
        for (int i = 0; i < 2; ++i) {
            int rA = wr * 128 + (4 + i) * 16 + l15;
#pragma unroll
            for (int ks = 0; ks < 2; ++ks)
                aC[i][ks] = *(const f16x8*)(buf + lch(rA, ks * 4 + l4));
        }
        P_PRE;
#pragma unroll
        for (int i = 0; i < 2; ++i)
#pragma unroll
            for (int n = 0; n < 4; ++n) {
                f32x4 v = acc[2 + i][n];
                v = MFMA_F16(aB[i][0], bfr[n][0], v, 0, 0, 0);
                v = MFMA_F16(aB[i][1], bfr[n][1], v, 0, 0, 0);
                acc[2 + i][n] = v;
            }
        P_POST;
        // ---- P2: read A m6,m7; stage B(t+2); MFMA m4,m5 ----
        f16x8 aD[2][2];
#pragma unroll
        for (int i = 0; i < 2; ++i) {
            int rA = wr * 128 + (6 + i) * 16 + l15;
#pragma unroll
            for (int ks = 0; ks < 2; ++ks)
                aD[i][ks] = *(const f16x8*)(buf + lch(rA, ks * 4 + l4));
        }
        if (st) stageB4(gB2, ldB, buf, tid);
        P_PRE;
#pragma unroll
        for (int i = 0; i < 2; ++i)
#pragma unroll
            for (int n = 0; n < 4; ++n) {
                f32x4 v = acc[4 + i][n];
                v = MFMA_F16(aC[i][0], bfr[n][0], v, 0, 0, 0);
                v = MFMA_F16(aC[i][1], bfr[n][1], v, 0, 0, 0);
                acc[4 + i][n] = v;
            }
        P_POST;
        // ---- P3: stage A(t+2); MFMA m6,m7; vmcnt ----
        if (st) stageA4(gA2, ldA, buf, tid);
        __builtin_amdgcn_s_setprio(1);
#pragma unroll
        for (int i = 0; i < 2; ++i)
#pragma unroll
            for (int n = 0; n < 4; ++n) {
                f32x4 v = acc[6 + i][n];
                v = MFMA_F16(aD[i][0], bfr[n][0], v, 0, 0, 0);
                v = MFMA_F16(aD[i][1], bfr[n][1], v, 0, 0, 0);
                acc[6 + i][n] = v;
            }
        __builtin_amdgcn_s_setprio(0);
        SB0;
        if (t + 2 < NT) {
            asm volatile("s_waitcnt vmcnt(8)" ::: "memory");
        } else if (t + 1 < NT) {
            asm volatile("s_waitcnt vmcnt(0)" ::: "memory");
        }
        SB0;
        __builtin_amdgcn_s_barrier();
    }
    int r0 = bx * 256 + wr * 128 + (l4 << 2);
    int c0 = by * 256 + wc * 64 + l15;
#pragma unroll
    for (int m = 0; m < 8; ++m)
#pragma unroll
        for (int n = 0; n < 4; ++n)
#pragma unroll
            for (int j = 0; j < 4; ++j) {
                int r = r0 + m * 16 + j;
                int c = c0 + n * 16;
                float v = acc[m][n][j];
                if (EPI == 0) {
                    Cm[(long long)z * sC + (long long)r * 1024 + c] = (_Float16)v;
                } else {
                    Co[(long long)r * 1024 + c] = tanhf(v);
                }
            }
}

// ---------- launch ----------

extern "C" void kernel_launch(void* const* d_in, const int* in_sizes, int n_in,
                              void* d_out, int out_size, void* d_ws, size_t ws_size,
                              hipStream_t stream) {
    const float* query = (const float*)d_in[0];
    const float* ctx = (const float*)d_in[1];
    const int* mask = (const int*)d_in[2];
    const float* Win = (const float*)d_in[3];
    const float* Wout = (const float*)d_in[4];
    float* outp = (float*)d_out;

    const long long MB = 1048576ll;
    // footprint: exactly 16G MiB (weights overlaid into dead slab regions).
    int G = 1;
    if ((long long)ws_size >= 512 * MB) G = 32;
    else if ((long long)ws_size >= 256 * MB) G = 16;
    else if ((long long)ws_size >= 128 * MB) G = 8;
    else if ((long long)ws_size >= 64 * MB) G = 4;
    else if ((long long)ws_size >= 32 * MB) G = 2;

    char* p = (char*)d_ws;
    const long long R = (long long)G * 1024;   // rows per chunk
    bf16_t* qint = (bf16_t*)p; p += 4 * G * MB;    // [R][2048] interleaved
    _Float16* qf = (_Float16*)p; p += 2 * G * MB;  // [R][1024]
    // slabA (4G MiB): win_int (4 MiB, GEMM1) -> ctx_int [R][2048] (GEMM2)
    //                 -> wf [R][1024] (lower 2G) + mixf [R][1024] (upper 2G)
    char* slabA = p; p += 4 * G * MB;
    bf16_t* win_int = (bf16_t*)slabA;
    bf16_t* ctx_int = (bf16_t*)slabA;
    _Float16* wf = (_Float16*)slabA;
    _Float16* mixf = (_Float16*)(slabA + 2 * G * MB);
    _Float16* ctxT = (_Float16*)p; p += 2 * G * MB;
    // slabC (4G MiB): qs_int (GEMM1 A) -> scores f32 (GEMM2/softmax) -> woutf (GEMM4 B)
    char* slabC = p;
    bf16_t* qs_int = (bf16_t*)slabC;
    float* scores = (float*)slabC;
    _Float16* woutf = (_Float16*)slabC;

    const long long LD = 1048576ll;  // 1024*1024 elements

    for (int b0 = 0; b0 < 32; b0 += G) {
        const float* qsrc = query + (long long)b0 * LD;
        const float* csrc = ctx + (long long)b0 * LD;
        // weights + query prep (win_int lives in slabA until prep_ctx overwrites it)
        split_int_k<<<1024, 256, 0, stream>>>(Win, win_int, 262144ll);
        split_int_k<<<(int)R, 256, 0, stream>>>(qsrc, qs_int, R * 256);
        // GEMM1: q = query @ Win^T (bf16x3) -> qint (interleaved) + qf (f16)
        gemm_x3_256<1><<<16 * G, 512, 0, stream>>>(
            qs_int, win_int, nullptr, 0, 0, 0, 4 * G, 4, nullptr, qint, qf);
        // fused ctx prep: ctx_int (over win_int, dead) + ctxT, reads ctx once
        prep_ctx_k<<<dim3(32, 32, G), dim3(32, 8, 1), 0, stream>>>(csrc, ctx_int, ctxT);
        // GEMM2: scores = q @ ctx^T (bf16x3) -> sentinel-masked scores (over qs_int)
        gemm_x3_256<0><<<16 * G, 512, 0, stream>>>(
            qint, ctx_int, mask + (long long)b0 * LD,
            2097152ll, 2097152ll, 1048576ll, 4, 4, scores, nullptr, nullptr);
        // softmax on sentinel-masked scores (mask not re-read) -> wf
        masked_softmax_k<<<(int)R, 256, 0, stream>>>(scores, wf);
        // Wout cast -> woutf (over scores, dead)
        cast_f16_k<<<2048, 256, 0, stream>>>(Wout, woutf, 524288ll);
        // GEMM3: mix = w @ ctxT^T (f16) -> mixf (over ctx_int upper half, dead)
        gemm_f16_256<0><<<16 * G, 512, 0, stream>>>(
            wf, wf, ctxT, 1024ll, 1024ll, 1048576ll, 1048576ll, 1048576ll,
            16, 1 << 20, 4, 4, mixf, nullptr);
        // GEMM4: out = tanh(mix @ W1^T + q @ W2^T), K=2048, A-switch at tile 16
        gemm_f16_256<1><<<16 * G, 512, 0, stream>>>(
            mixf, qf, woutf, 1024ll, 2048ll, 0, 0, 0,
            32, 16, 4 * G, 4, nullptr, outp + (long long)b0 * LD);
    }
}

// Round 12
// 761.902 us; speedup vs baseline: 1.1778x; 1.0213x over previous
//
#include <hip/hip_runtime.h>
#include <math.h>

typedef __bf16 bf16_t;
typedef __bf16 bf16x4 __attribute__((ext_vector_type(4)));
typedef __bf16 bf16x8 __attribute__((ext_vector_type(8)));
typedef _Float16 f16x4 __attribute__((ext_vector_type(4)));
typedef _Float16 f16x8 __attribute__((ext_vector_type(8)));
typedef float f32x4 __attribute__((ext_vector_type(4)));
typedef int i32x4 __attribute__((ext_vector_type(4)));

#define MFMA_BF16 __builtin_amdgcn_mfma_f32_16x16x32_bf16
#define MFMA_F16  __builtin_amdgcn_mfma_f32_16x16x32_f16

// phase sync: barrier, drain own ds_reads, pin, boost
#define P_PRE                                         \
    __builtin_amdgcn_sched_barrier(0);                \
    __builtin_amdgcn_s_barrier();                     \
    asm volatile("s_waitcnt lgkmcnt(0)" ::: "memory");\
    __builtin_amdgcn_sched_barrier(0);                \
    __builtin_amdgcn_s_setprio(1)
#define P_POST                                        \
    __builtin_amdgcn_s_setprio(0);                    \
    __builtin_amdgcn_sched_barrier(0);                \
    __builtin_amdgcn_s_barrier()

// ---------- helpers ----------

__device__ __forceinline__ bf16_t to_bf16_rne(float x, float& rep) {
    unsigned u = __builtin_bit_cast(unsigned, x);
    unsigned r = u + 0x7fffu + ((u >> 16) & 1u);
    unsigned short h = (unsigned short)(r >> 16);
    rep = __builtin_bit_cast(float, ((unsigned)h) << 16);
    return __builtin_bit_cast(bf16_t, h);
}

__device__ __forceinline__ void g2l16(const void* g, void* l) {
    __builtin_amdgcn_global_load_lds(
        (const __attribute__((address_space(1))) unsigned int*)g,
        (__attribute__((address_space(3))) unsigned int*)l, 16, 0, 0);
}

// swizzled element offset of 16B-chunk (row r in 0..255, chunk j in 0..7);
// rows are 128B. j ^= (r&7): involution, applied on pre-swizzled global
// source AND on every ds_read. 16-row read spans -> 2-way (free) bank aliasing.
__device__ __forceinline__ int lch(int r, int j) {
    return (r * 8 + (j ^ (r & 7))) * 8;
}

// stage A half-tile (256 rows x 128B) into buf[0:16384); 4 loads/thread
template <typename T>
__device__ __forceinline__ void stageA4(const T* __restrict__ gA, long long ldA,
                                        T* buf, int tid) {
    int wid = tid >> 6, lane = tid & 63;
#pragma unroll
    for (int i = 0; i < 4; ++i) {
        int cb = i * 512 + wid * 64;
        int c = cb + lane;
        int r = c >> 3, j = (c & 7) ^ (r & 7);
        g2l16(gA + (long long)r * ldA + j * 8, buf + (size_t)cb * 8);
    }
}

// stage B half-tile into buf[16384:32768); 4 loads/thread
template <typename T>
__device__ __forceinline__ void stageB4(const T* __restrict__ gB, long long ldB,
                                        T* buf, int tid) {
    int wid = tid >> 6, lane = tid & 63;
#pragma unroll
    for (int i = 0; i < 4; ++i) {
        int cb = i * 512 + wid * 64;
        int c = cb + lane;
        int r = c >> 3, j = (c & 7) ^ (r & 7);
        g2l16(gB + (long long)r * ldB + j * 8, buf + 16384 + (size_t)cb * 8);
    }
}

template <typename T>
__device__ __forceinline__ void stage2(const T* __restrict__ gA, long long ldA,
                                       const T* __restrict__ gB, long long ldB,
                                       T* buf, int tid) {
    stageA4(gA, ldA, buf, tid);
    stageB4(gB, ldB, buf, tid);
}

// ---------- elementwise prep kernels ----------

// f32 [rows][1024] -> interleaved bf16 hi/lo: row stride 2048, 32-k blocks [32 hi|32 lo]
__global__ __launch_bounds__(256) void split_int_k(const float* __restrict__ in,
                                                   bf16_t* __restrict__ out,
                                                   long long n4) {
    long long i = (long long)blockIdx.x * 256 + threadIdx.x;
    if (i >= n4) return;
    f32x4 v = ((const f32x4*)in)[i];
    bf16x4 hv, lv;
#pragma unroll
    for (int j = 0; j < 4; ++j) {
        float rep;
        hv[j] = to_bf16_rne(v[j], rep);
        float res = v[j] - rep;
        float rep2;
        lv[j] = to_bf16_rne(res, rep2);
    }
    long long row = i >> 8;
    int k = (int)(i & 255) * 4;
    long long base = row * 2048 + ((k >> 5) << 6) + (k & 31);
    *(bf16x4*)(out + base) = hv;
    *(bf16x4*)(out + base + 32) = lv;
}

__global__ __launch_bounds__(256) void cast_f16_k(const float* __restrict__ in,
                                                  _Float16* __restrict__ o, long long n4) {
    long long i = (long long)blockIdx.x * 256 + threadIdx.x;
    if (i >= n4) return;
    f32x4 v = ((const f32x4*)in)[i];
    f16x4 h;
#pragma unroll
    for (int j = 0; j < 4; ++j) h[j] = (_Float16)v[j];
    ((f16x4*)o)[i] = h;
}

// fused: ctx chunk [G][1024][1024] f32 -> ctx_int (interleaved hi/lo bf16, rows 2048)
//        AND ctxT [G][1024(d)][1024(k)] f16   (reads ctx ONCE)
__global__ __launch_bounds__(256) void prep_ctx_k(const float* __restrict__ ctx,
                                                  bf16_t* __restrict__ ctx_int,
                                                  _Float16* __restrict__ ctxT) {
    __shared__ _Float16 tl[32][33];
    int b = blockIdx.z;
    int k0 = blockIdx.x * 32, d0 = blockIdx.y * 32;
    const float* src = ctx + ((long long)b * 1024 + k0) * 1024 + d0;
    int x = threadIdx.x, y = threadIdx.y;  // 32 x 8
#pragma unroll
    for (int i = 0; i < 4; ++i) {
        int k = y + i * 8;
        float v = src[(long long)k * 1024 + x];
        float rep;
        bf16_t hb = to_bf16_rne(v, rep);
        float rep2;
        bf16_t lb = to_bf16_rne(v - rep, rep2);
        long long rb = ((long long)b * 1024 + k0 + k) * 2048 + d0 * 2 + x;
        ctx_int[rb] = hb;
        ctx_int[rb + 32] = lb;
        tl[x][k] = (_Float16)v;
    }
    __syncthreads();
    _Float16* dst = ctxT + ((long long)b * 1024 + d0) * 1024 + k0;
#pragma unroll
    for (int i = 0; i < 4; ++i) {
        int dd = y + i * 8;
        dst[(long long)dd * 1024 + x] = tl[dd][x];
    }
}

// per-row masked softmax: w_k = m_k*exp(s_k - max)/sum  (fp32 in, f16 out)
__global__ __launch_bounds__(256) void masked_softmax_k(const float* __restrict__ s,
                                                        const int* __restrict__ m,
                                                        _Float16* __restrict__ w) {
    long long row = blockIdx.x;
    const f32x4* sr = (const f32x4*)(s + row * 1024);
    const i32x4* mr = (const i32x4*)(m + row * 1024);
    f16x4* wr_ = (f16x4*)(w + row * 1024);
    int t = threadIdx.x;
    int lane = t & 63, wid = t >> 6;
    f32x4 v = sr[t];
    i32x4 mk = mr[t];
    float mx = -3.0e38f;
#pragma unroll
    for (int i = 0; i < 4; ++i)
        if (mk[i]) mx = fmaxf(mx, v[i]);
#pragma unroll
    for (int off = 32; off; off >>= 1) mx = fmaxf(mx, __shfl_xor(mx, off));
    __shared__ float rm[4], rs[4];
    if (!lane) rm[wid] = mx;
    __syncthreads();
    mx = fmaxf(fmaxf(rm[0], rm[1]), fmaxf(rm[2], rm[3]));
    float sum = 0.f;
    f32x4 e;
#pragma unroll
    for (int i = 0; i < 4; ++i) {
        e[i] = mk[i] ? expf(v[i] - mx) : 0.f;
        sum += e[i];
    }
#pragma unroll
    for (int off = 32; off; off >>= 1) sum += __shfl_xor(sum, off);
    if (!lane) rs[wid] = sum;
    __syncthreads();
    sum = rs[0] + rs[1] + rs[2] + rs[3];
    float inv = sum > 0.f ? 1.0f / sum : 0.f;
    f16x4 o;
#pragma unroll
    for (int i = 0; i < 4; ++i) o[i] = (_Float16)(e[i] * inv);
    wr_[t] = o;
}

// ---------- 256x256 dbuf bf16x3 GEMM, 4-phase interleave ----------
// A,B: interleaved hi/lo pair layout, rows of 2048 elements, K=1024 (BK=32).
// Per K-tile: P0{read B + m01 | MFMA m01} P1{read m2345 | MFMA m23}
// P2{read m67, stage B(t+2) | MFMA m45} P3{stage A(t+2), vmcnt(8) | MFMA m67}.
// B-half overwrite safe after P0's drain+bar; A-half after P2's. vmcnt(8)
// at P3 = "tile t+1's 8 loads complete"; never 0 until tail.
// EPI 0: f32 scores (ld 1024, +z*sC). EPI 1: qint interleaved + qf f16.
template <int EPI>
__global__ __launch_bounds__(512, 2) void gemm_x3_256(
    const bf16_t* __restrict__ Aint, const bf16_t* __restrict__ Bint,
    long long sA, long long sB, long long sC, int nbx, int nby,
    float* __restrict__ Cs, bf16_t* __restrict__ Qint, _Float16* __restrict__ Qf) {
    __shared__ bf16_t lds[65536];
    const int NT = 32;
    int tid = threadIdx.x, lane = tid & 63, wid = tid >> 6;
    int wr = wid >> 2, wc = wid & 3;
    int nwg = gridDim.x;
    int bid = blockIdx.x;
    int lid = (bid & 7) * (nwg >> 3) + (bid >> 3);   // XCD-contiguous remap
    int by = lid % nby;
    int t2_ = lid / nby;
    int bx = t2_ % nbx;
    int z = t2_ / nbx;
    const bf16_t* At = Aint + (long long)z * sA + (long long)bx * 256 * 2048;
    const bf16_t* Bt = Bint + (long long)z * sB + (long long)by * 256 * 2048;
    stage2(At, 2048ll, Bt, 2048ll, lds, tid);
    stage2(At + 64, 2048ll, Bt + 64, 2048ll, lds + 32768, tid);
    f32x4 acc[8][4] = {};
    int l15 = lane & 15, l4 = lane >> 4;
    asm volatile("s_waitcnt vmcnt(8)" ::: "memory");
    __builtin_amdgcn_sched_barrier(0);
    __builtin_amdgcn_s_barrier();
    for (int t = 0; t < NT; ++t) {
        bf16_t* buf = lds + (size_t)(t & 1) * 32768;
        bf16_t* bufB = buf + 16384;
        const bf16_t* At2 = At + (long long)(t + 2) * 64;
        const bf16_t* Bt2 = Bt + (long long)(t + 2) * 64;
        bool st = (t + 2 < NT);
        // ---- P0: read B all + A m0,m1; MFMA m0,m1 ----
        bf16x8 bh[4], bl[4], ahA[2], alA[2];
#pragma unroll
        for (int n = 0; n < 4; ++n) {
            int rB = wc * 64 + n * 16 + l15;
            bh[n] = *(const bf16x8*)(bufB + lch(rB, l4));
            bl[n] = *(const bf16x8*)(bufB + lch(rB, 4 + l4));
        }
#pragma unroll
        for (int i = 0; i < 2; ++i) {
            int rA = wr * 128 + i * 16 + l15;
            ahA[i] = *(const bf16x8*)(buf + lch(rA, l4));
            alA[i] = *(const bf16x8*)(buf + lch(rA, 4 + l4));
        }
        P_PRE;
#pragma unroll
        for (int i = 0; i < 2; ++i)
#pragma unroll
            for (int n = 0; n < 4; ++n) {
                f32x4 a = acc[i][n];
                a = MFMA_BF16(ahA[i], bh[n], a, 0, 0, 0);
                a = MFMA_BF16(ahA[i], bl[n], a, 0, 0, 0);
                a = MFMA_BF16(alA[i], bh[n], a, 0, 0, 0);
                acc[i][n] = a;
            }
        P_POST;
        // ---- P1: read A m2..m5; MFMA m2,m3 ----
        bf16x8 ahB[2], alB[2], ahC[2], alC[2];
#pragma unroll
        for (int i = 0; i < 2; ++i) {
            int rA = wr * 128 + (2 + i) * 16 + l15;
            ahB[i] = *(const bf16x8*)(buf + lch(rA, l4));
            alB[i] = *(const bf16x8*)(buf + lch(rA, 4 + l4));
        }
#pragma unroll
        for (int i = 0; i < 2; ++i) {
            int rA = wr * 128 + (4 + i) * 16 + l15;
            ahC[i] = *(const bf16x8*)(buf + lch(rA, l4));
            alC[i] = *(const bf16x8*)(buf + lch(rA, 4 + l4));
        }
        P_PRE;
#pragma unroll
        for (int i = 0; i < 2; ++i)
#pragma unroll
            for (int n = 0; n < 4; ++n) {
                f32x4 a = acc[2 + i][n];
                a = MFMA_BF16(ahB[i], bh[n], a, 0, 0, 0);
                a = MFMA_BF16(ahB[i], bl[n], a, 0, 0, 0);
                a = MFMA_BF16(alB[i], bh[n], a, 0, 0, 0);
                acc[2 + i][n] = a;
            }
        P_POST;
        // ---- P2: read A m6,m7; stage B(t+2); MFMA m4,m5 ----
        bf16x8 ahD[2], alD[2];
#pragma unroll
        for (int i = 0; i < 2; ++i) {
            int rA = wr * 128 + (6 + i) * 16 + l15;
            ahD[i] = *(const bf16x8*)(buf + lch(rA, l4));
            alD[i] = *(const bf16x8*)(buf + lch(rA, 4 + l4));
        }
        if (st) stageB4(Bt2, 2048ll, buf, tid);
        P_PRE;
#pragma unroll
        for (int i = 0; i < 2; ++i)
#pragma unroll
            for (int n = 0; n < 4; ++n) {
                f32x4 a = acc[4 + i][n];
                a = MFMA_BF16(ahC[i], bh[n], a, 0, 0, 0);
                a = MFMA_BF16(ahC[i], bl[n], a, 0, 0, 0);
                a = MFMA_BF16(alC[i], bh[n], a, 0, 0, 0);
                acc[4 + i][n] = a;
            }
        P_POST;
        // ---- P3: stage A(t+2); vmcnt; MFMA m6,m7 ----
        if (st) stageA4(At2, 2048ll, buf, tid);
        __builtin_amdgcn_s_setprio(1);
#pragma unroll
        for (int i = 0; i < 2; ++i)
#pragma unroll
            for (int n = 0; n < 4; ++n) {
                f32x4 a = acc[6 + i][n];
                a = MFMA_BF16(ahD[i], bh[n], a, 0, 0, 0);
                a = MFMA_BF16(ahD[i], bl[n], a, 0, 0, 0);
                a = MFMA_BF16(alD[i], bh[n], a, 0, 0, 0);
                acc[6 + i][n] = a;
            }
        __builtin_amdgcn_s_setprio(0);
        __builtin_amdgcn_sched_barrier(0);
        if (t + 2 < NT) {
            asm volatile("s_waitcnt vmcnt(8)" ::: "memory");
        } else if (t + 1 < NT) {
            asm volatile("s_waitcnt vmcnt(0)" ::: "memory");
        }
        __builtin_amdgcn_sched_barrier(0);
        __builtin_amdgcn_s_barrier();
    }
    int r0 = bx * 256 + wr * 128 + (l4 << 2);
    int c0 = by * 256 + wc * 64 + l15;
#pragma unroll
    for (int m = 0; m < 8; ++m)
#pragma unroll
        for (int n = 0; n < 4; ++n)
#pragma unroll
            for (int j = 0; j < 4; ++j) {
                int r = r0 + m * 16 + j;
                int c = c0 + n * 16;
                float v = acc[m][n][j];
                if (EPI == 0) {
                    Cs[(long long)z * sC + (long long)r * 1024 + c] = v;
                } else {
                    float rep;
                    bf16_t hb = to_bf16_rne(v, rep);
                    float res = v - rep;
                    float rep2;
                    bf16_t lb = to_bf16_rne(res, rep2);
                    long long rb = (long long)r * 2048 + ((c >> 5) << 6) + (c & 31);
                    Qint[rb] = hb;
                    Qint[rb + 32] = lb;
                    Qf[(long long)r * 1024 + c] = (_Float16)v;
                }
            }
}

// ---------- 256x256 dbuf f16 GEMM, 4-phase interleave (BK=64) ----------
// A rows K-contig (ldA), optional A-source switch at tile swt. B rows K-contig.
// EPI 0: f16 out (ld 1024, +z*sC). EPI 1: f32 tanh out (ld 1024).
template <int EPI>
__global__ __launch_bounds__(512, 2) void gemm_f16_256(
    const _Float16* __restrict__ A1, const _Float16* __restrict__ A2,
    const _Float16* __restrict__ B,
    long long ldA, long long ldB, long long sA, long long sB, long long sC,
    int NT, int swt, int nbx, int nby,
    _Float16* __restrict__ Cm, float* __restrict__ Co) {
    __shared__ _Float16 lds[65536];
    int tid = threadIdx.x, lane = tid & 63, wid = tid >> 6;
    int wr = wid >> 2, wc = wid & 3;
    int nwg = gridDim.x;
    int bid = blockIdx.x;
    int lid = (bid & 7) * (nwg >> 3) + (bid >> 3);
    int by = lid % nby;
    int t2_ = lid / nby;
    int bx = t2_ % nbx;
    int z = t2_ / nbx;
    const _Float16* A1t = A1 + (long long)z * sA + (long long)bx * 256 * ldA;
    const _Float16* A2t = A2 + (long long)bx * 256 * ldA;
    const _Float16* Bt = B + (long long)z * sB + (long long)by * 256 * ldB;
    stage2((0 < swt) ? A1t : A2t, ldA, Bt, ldB, lds, tid);
    stage2((1 < swt) ? A1t + 64 : A2t + (long long)(1 - swt) * 64, ldA, Bt + 64, ldB,
           lds + 32768, tid);
    f32x4 acc[8][4] = {};
    int l15 = lane & 15, l4 = lane >> 4;
    asm volatile("s_waitcnt vmcnt(8)" ::: "memory");
    __builtin_amdgcn_sched_barrier(0);
    __builtin_amdgcn_s_barrier();
    for (int t = 0; t < NT; ++t) {
        _Float16* buf = lds + (size_t)(t & 1) * 32768;
        _Float16* bufB = buf + 16384;
        int tt = t + 2;
        bool st = (tt < NT);
        const _Float16* gA2 =
            (tt < swt) ? A1t + (long long)tt * 64 : A2t + (long long)(tt - swt) * 64;
        const _Float16* gB2 = Bt + (long long)tt * 64;
        // ---- P0: read B all + A m0,m1; MFMA m0,m1 ----
        f16x8 bfr[4][2], aA[2][2];
#pragma unroll
        for (int n = 0; n < 4; ++n) {
            int rB = wc * 64 + n * 16 + l15;
#pragma unroll
            for (int ks = 0; ks < 2; ++ks)
                bfr[n][ks] = *(const f16x8*)(bufB + lch(rB, ks * 4 + l4));
        }
#pragma unroll
        for (int i = 0; i < 2; ++i) {
            int rA = wr * 128 + i * 16 + l15;
#pragma unroll
            for (int ks = 0; ks < 2; ++ks)
                aA[i][ks] = *(const f16x8*)(buf + lch(rA, ks * 4 + l4));
        }
        P_PRE;
#pragma unroll
        for (int i = 0; i < 2; ++i)
#pragma unroll
            for (int n = 0; n < 4; ++n) {
                f32x4 v = acc[i][n];
                v = MFMA_F16(aA[i][0], bfr[n][0], v, 0, 0, 0);
                v = MFMA_F16(aA[i][1], bfr[n][1], v, 0, 0, 0);
                acc[i][n] = v;
            }
        P_POST;
        // ---- P1: read A m2..m5; MFMA m2,m3 ----
        f16x8 aB[2][2], aC[2][2];
#pragma unroll
        for (int i = 0; i < 2; ++i) {
            int rA = wr * 128 + (2 + i) * 16 + l15;
#pragma unroll
            for (int ks = 0; ks < 2; ++ks)
                aB[i][ks] = *(const f16x8*)(buf + lch(rA, ks * 4 + l4));
        }
#pragma unroll
        for (int i = 0; i < 2; ++i) {
            int rA = wr * 128 + (4 + i) * 16 + l15;
#pragma unroll
            for (int ks = 0; ks < 2; ++ks)
                aC[i][ks] = *(const f16x8*)(buf + lch(rA, ks * 4 + l4));
        }
        P_PRE;
#pragma unroll
        for (int i = 0; i < 2; ++i)
#pragma unroll
            for (int n = 0; n < 4; ++n) {
                f32x4 v = acc[2 + i][n];
                v = MFMA_F16(aB[i][0], bfr[n][0], v, 0, 0, 0);
                v = MFMA_F16(aB[i][1], bfr[n][1], v, 0, 0, 0);
                acc[2 + i][n] = v;
            }
        P_POST;
        // ---- P2: read A m6,m7; stage B(t+2); MFMA m4,m5 ----
        f16x8 aD[2][2];
#pragma unroll
        for (int i = 0; i < 2; ++i) {
            int rA = wr * 128 + (6 + i) * 16 + l15;
#pragma unroll
            for (int ks = 0; ks < 2; ++ks)
                aD[i][ks] = *(const f16x8*)(buf + lch(rA, ks * 4 + l4));
        }
        if (st) stageB4(gB2, ldB, buf, tid);
        P_PRE;
#pragma unroll
        for (int i = 0; i < 2; ++i)
#pragma unroll
            for (int n = 0; n < 4; ++n) {
                f32x4 v = acc[4 + i][n];
                v = MFMA_F16(aC[i][0], bfr[n][0], v, 0, 0, 0);
                v = MFMA_F16(aC[i][1], bfr[n][1], v, 0, 0, 0);
                acc[4 + i][n] = v;
            }
        P_POST;
        // ---- P3: stage A(t+2); MFMA m6,m7; vmcnt ----
        if (st) stageA4(gA2, ldA, buf, tid);
        __builtin_amdgcn_s_setprio(1);
#pragma unroll
        for (int i = 0; i < 2; ++i)
#pragma unroll
            for (int n = 0; n < 4; ++n) {
                f32x4 v = acc[6 + i][n];
                v = MFMA_F16(aD[i][0], bfr[n][0], v, 0, 0, 0);
                v = MFMA_F16(aD[i][1], bfr[n][1], v, 0, 0, 0);
                acc[6 + i][n] = v;
            }
        __builtin_amdgcn_s_setprio(0);
        __builtin_amdgcn_sched_barrier(0);
        if (t + 2 < NT) {
            asm volatile("s_waitcnt vmcnt(8)" ::: "memory");
        } else if (t + 1 < NT) {
            asm volatile("s_waitcnt vmcnt(0)" ::: "memory");
        }
        __builtin_amdgcn_sched_barrier(0);
        __builtin_amdgcn_s_barrier();
    }
    int r0 = bx * 256 + wr * 128 + (l4 << 2);
    int c0 = by * 256 + wc * 64 + l15;
#pragma unroll
    for (int m = 0; m < 8; ++m)
#pragma unroll
        for (int n = 0; n < 4; ++n)
#pragma unroll
            for (int j = 0; j < 4; ++j) {
                int r = r0 + m * 16 + j;
                int c = c0 + n * 16;
                float v = acc[m][n][j];
                if (EPI == 0) {
                    Cm[(long long)z * sC + (long long)r * 1024 + c] = (_Float16)v;
                } else {
                    Co[(long long)r * 1024 + c] = tanhf(v);
                }
            }
}

// ---------- launch ----------

extern "C" void kernel_launch(void* const* d_in, const int* in_sizes, int n_in,
                              void* d_out, int out_size, void* d_ws, size_t ws_size,
                              hipStream_t stream) {
    const float* query = (const float*)d_in[0];
    const float* ctx = (const float*)d_in[1];
    const int* mask = (const int*)d_in[2];
    const float* Win = (const float*)d_in[3];
    const float* Wout = (const float*)d_in[4];
    float* outp = (float*)d_out;

    const long long MB = 1048576ll;
    // footprint: exactly 16G MiB (weights overlaid into dead slab regions).
    int G = 1;
    if ((long long)ws_size >= 512 * MB) G = 32;
    else if ((long long)ws_size >= 256 * MB) G = 16;
    else if ((long long)ws_size >= 128 * MB) G = 8;
    else if ((long long)ws_size >= 64 * MB) G = 4;
    else if ((long long)ws_size >= 32 * MB) G = 2;

    char* p = (char*)d_ws;
    const long long R = (long long)G * 1024;   // rows per chunk
    bf16_t* qint = (bf16_t*)p; p += 4 * G * MB;    // [R][2048] interleaved
    _Float16* qf = (_Float16*)p; p += 2 * G * MB;  // [R][1024]
    // slabA (4G MiB): win_int (4 MiB, GEMM1) -> ctx_int [R][2048] (GEMM2)
    //                 -> wf [R][1024] (lower 2G) + mixf [R][1024] (upper 2G)
    char* slabA = p; p += 4 * G * MB;
    bf16_t* win_int = (bf16_t*)slabA;
    bf16_t* ctx_int = (bf16_t*)slabA;
    _Float16* wf = (_Float16*)slabA;
    _Float16* mixf = (_Float16*)(slabA + 2 * G * MB);
    _Float16* ctxT = (_Float16*)p; p += 2 * G * MB;
    // slabC (4G MiB): qs_int (GEMM1 A) -> scores f32 (GEMM2/softmax) -> woutf (GEMM4 B)
    char* slabC = p;
    bf16_t* qs_int = (bf16_t*)slabC;
    float* scores = (float*)slabC;
    _Float16* woutf = (_Float16*)slabC;

    const long long LD = 1048576ll;  // 1024*1024 elements

    for (int b0 = 0; b0 < 32; b0 += G) {
        const float* qsrc = query + (long long)b0 * LD;
        const float* csrc = ctx + (long long)b0 * LD;
        // weights + query prep (win_int lives in slabA until prep_ctx overwrites it)
        split_int_k<<<1024, 256, 0, stream>>>(Win, win_int, 262144ll);
        split_int_k<<<(int)R, 256, 0, stream>>>(qsrc, qs_int, R * 256);
        // GEMM1: q = query @ Win^T (bf16x3) -> qint (interleaved) + qf (f16)
        gemm_x3_256<1><<<16 * G, 512, 0, stream>>>(
            qs_int, win_int, 0, 0, 0, 4 * G, 4, nullptr, qint, qf);
        // fused ctx prep: ctx_int (over win_int, dead) + ctxT, reads ctx once
        prep_ctx_k<<<dim3(32, 32, G), dim3(32, 8, 1), 0, stream>>>(csrc, ctx_int, ctxT);
        // GEMM2: scores = q @ ctx^T (bf16x3) -> scores (over qs_int, dead)
        gemm_x3_256<0><<<16 * G, 512, 0, stream>>>(
            qint, ctx_int, 2097152ll, 2097152ll, 1048576ll, 4, 4,
            scores, nullptr, nullptr);
        // softmax -> wf (over ctx_int lower half, dead)
        masked_softmax_k<<<(int)R, 256, 0, stream>>>(
            scores, mask + (long long)b0 * 1024 * 1024, wf);
        // Wout cast -> woutf (over scores, dead)
        cast_f16_k<<<2048, 256, 0, stream>>>(Wout, woutf, 524288ll);
        // GEMM3: mix = w @ ctxT^T (f16) -> mixf (over ctx_int upper half, dead)
        gemm_f16_256<0><<<16 * G, 512, 0, stream>>>(
            wf, wf, ctxT, 1024ll, 1024ll, 1048576ll, 1048576ll, 1048576ll,
            16, 1 << 20, 4, 4, mixf, nullptr);
        // GEMM4: out = tanh(mix @ W1^T + q @ W2^T), K=2048, A-switch at tile 16
        gemm_f16_256<1><<<16 * G, 512, 0, stream>>>(
            mixf, qf, woutf, 1024ll, 2048ll, 0, 0, 0,
            32, 16, 4 * G, 4, nullptr, outp + (long long)b0 * LD);
    }
}